// Round 9
// baseline (1290.298 us; speedup 1.0000x reference)
//
#include <hip/hip_runtime.h>
#include <math.h>

#define NB 16384
#define DIN 768

typedef _Float16 f16x8 __attribute__((ext_vector_type(8)));
typedef float f32x16 __attribute__((ext_vector_type(16)));

// ---------------- small kernels ----------------

__global__ void k_zero2(float* a, float* b) {
    if (threadIdx.x == 0) { *a = 0.f; *b = 0.f; }
}

__global__ void k_norm(const float* __restrict__ x, const float* __restrict__ m,
                       const float* __restrict__ s, float* __restrict__ xn) {
    int i = blockIdx.x * 256 + threadIdx.x;          // 16384*768 total
    int j = i % DIN;
    xn[i] = (x[i] - m[j]) / s[j];
}

// one 64-lane wave per codebook row; writes ||E||^2 * 4096 (r*-32, E*256 scaling)
__global__ void k_cbnorm(const float* __restrict__ cb, float* __restrict__ cbn) {
    int row = blockIdx.x * 4 + (threadIdx.x >> 6);
    int lane = threadIdx.x & 63;
    const float* p = cb + (size_t)row * 128;
    float v0 = p[lane], v1 = p[lane + 64];
    float s = v0 * v0 + v1 * v1;
    #pragma unroll
    for (int m = 32; m >= 1; m >>= 1) s += __shfl_xor(s, m, 64);
    if (lane == 0) cbn[row] = s * 4096.f;
}

// split fp32 rows (n x 128) into fp16 hi|lo layout (n x 256): [hi(128) | lo(128)]
__global__ void k_split(const float* __restrict__ src, _Float16* __restrict__ dst,
                        float scale) {
    int i = blockIdx.x * 256 + threadIdx.x;   // n*128 elements
    int row = i >> 7, d = i & 127;
    float v = src[i] * scale;
    _Float16 hi = (_Float16)v;
    dst[(size_t)row * 256 + d] = hi;
    dst[(size_t)row * 256 + 128 + d] = (_Float16)(v - (float)hi);
}

// E split into per-chunk granule layout (64-code chunks): chunk ch = c>>6;
// halfs offset = q*2097152 + ch*16384 + slice*512 + (c&63)*8 + (k&7)
// slice = k>>3 (hi) / 16 + (k>>3) (lo). Scale 256.
// v7 consumes this with DIRECT per-lane 16B global loads (no LDS).
__global__ void k_esplit(const float* __restrict__ cb, _Float16* __restrict__ Esp) {
    int i = blockIdx.x * 256 + threadIdx.x;   // 4*8192*128 total
    int q = i >> 20;
    int rem = i & 1048575;
    int c = rem >> 7, k = rem & 127;
    float v = cb[i] * 256.f;
    _Float16 hi = (_Float16)v;
    _Float16 lo = (_Float16)(v - (float)hi);
    int sh = k >> 3, j = k & 7;
    size_t base = (size_t)q * 2097152 + (size_t)(c >> 6) * 16384 + (size_t)(c & 63) * 8 + j;
    Esp[base + (size_t)sh * 512] = hi;
    Esp[base + (size_t)(16 + sh) * 512] = lo;
}

// ---------------- weight transpose-split into chunked granule layout ----------
// W (K x N fp32) -> Wt halfs, granule (kc, s, c): ((kc*8+s)*N + c)*8 + j
// k = kc*32 + t*16 + g*8 + j ; s = t*2+g (hi), 4+t*2+g (lo). Scale 256.
__global__ void k_wsplit(const float* __restrict__ W, _Float16* __restrict__ Wt,
                         int K, int N) {
    int i = blockIdx.x * 256 + threadIdx.x;   // K*N total
    int k = i / N, c = i - k * N;
    float v = W[i] * 256.f;
    _Float16 hi = (_Float16)v;
    _Float16 lo = (_Float16)(v - (float)hi);
    int kc = k >> 5, kin = k & 31;
    int t = kin >> 4, gg = (kin >> 3) & 1, j = kin & 7;
    size_t base = ((size_t)(kc * 8) * N + c) * 8 + j;
    Wt[base + (size_t)(t * 2 + gg) * N * 8] = hi;
    Wt[base + (size_t)(4 + t * 2 + gg) * N * 8] = lo;
}

// ---------------- fused MFMA Linear + ReLU + RMSNorm ----------------
// v2: COMPUTE product-major (tt inner), bitwise identical accumulation order.
template <int N>
__global__ __launch_bounds__(512, 2) void k_mfma_rms(
    const float* __restrict__ A, const _Float16* __restrict__ Wt,
    const float* __restrict__ bias, const float* __restrict__ g,
    float* __restrict__ out, int K) {
    constexpr int CT = N / 128;               // col-tiles per wave
    __shared__ __align__(16) _Float16 Bs[2][N * 64];
    __shared__ float ssbuf[64][4];
    const int tid = threadIdx.x;
    const int w = tid >> 6, lane = tid & 63;
    const int wr = w >> 2, wc = w & 3;
    const int g32 = lane >> 5, cl = lane & 31;
    const int row0 = blockIdx.x * 64;
    const int NC = K >> 5;                    // chunks of 32 k (always even)

    const float* ap = A + (size_t)(row0 + wr * 32 + cl) * K + g32 * 8;

    f32x16 acc[CT];
    #pragma unroll
    for (int tt = 0; tt < CT; tt++)
        #pragma unroll
        for (int m = 0; m < 16; m++) acc[tt][m] = 0.f;

    float4 Ar0[4], Ar1[4];

    auto STAGE = [&](int ch, int b) {
        const _Float16* gp = Wt + (size_t)ch * 8 * N * 8;
        #pragma unroll
        for (int p = 0; p < N / 64; p++) {
            int f = tid + 512 * p;
            __builtin_amdgcn_global_load_lds(
                (const __attribute__((address_space(1))) void*)(gp + (size_t)f * 8),
                (__attribute__((address_space(3))) void*)(&Bs[b][(size_t)f * 8]),
                16, 0, 0);
        }
    };
    auto AISSUE = [&](int ch, float4* Ar) {
        const float* bsrc = ap + ch * 32;
        Ar[0] = *(const float4*)(bsrc);
        Ar[1] = *(const float4*)(bsrc + 4);
        Ar[2] = *(const float4*)(bsrc + 16);
        Ar[3] = *(const float4*)(bsrc + 20);
    };
    auto COMPUTE = [&](int b, const float4* Ar) {
        #pragma unroll
        for (int t = 0; t < 2; t++) {
            float vv[8] = {Ar[t * 2].x, Ar[t * 2].y, Ar[t * 2].z, Ar[t * 2].w,
                           Ar[t * 2 + 1].x, Ar[t * 2 + 1].y, Ar[t * 2 + 1].z, Ar[t * 2 + 1].w};
            f16x8 ah, al;
            #pragma unroll
            for (int j = 0; j < 8; j++) {
                float v = vv[j] * 16.f;
                _Float16 h = (_Float16)v;
                ah[j] = h;
                al[j] = (_Float16)(v - (float)h);
            }
            f16x8 bh[CT], bl[CT];
            #pragma unroll
            for (int tt = 0; tt < CT; tt++) {
                int c = wc * (N / 4) + tt * 32 + cl;
                bh[tt] = *(const f16x8*)&Bs[b][((size_t)(t * 2 + g32) * N + c) * 8];
                bl[tt] = *(const f16x8*)&Bs[b][((size_t)(4 + t * 2 + g32) * N + c) * 8];
            }
            #pragma unroll
            for (int tt = 0; tt < CT; tt++)
                acc[tt] = __builtin_amdgcn_mfma_f32_32x32x16_f16(ah, bh[tt], acc[tt], 0, 0, 0);
            #pragma unroll
            for (int tt = 0; tt < CT; tt++)
                acc[tt] = __builtin_amdgcn_mfma_f32_32x32x16_f16(al, bh[tt], acc[tt], 0, 0, 0);
            #pragma unroll
            for (int tt = 0; tt < CT; tt++)
                acc[tt] = __builtin_amdgcn_mfma_f32_32x32x16_f16(ah, bl[tt], acc[tt], 0, 0, 0);
        }
    };

    AISSUE(0, Ar0);
    STAGE(0, 0);
    for (int ch = 0; ch < NC; ch += 2) {
        __syncthreads();                      // drains stage(ch) + A loads
        STAGE(ch + 1, 1);
        AISSUE(ch + 1, Ar1);
        COMPUTE(0, Ar0);
        __syncthreads();                      // drains stage(ch+1)
        if (ch + 2 < NC) { STAGE(ch + 2, 0); AISSUE(ch + 2, Ar0); }
        COMPUTE(1, Ar1);
    }

    // epilogue: /4096 + bias + relu + rmsnorm
    constexpr float INV = 1.f / 4096.f;
    float bb[CT], gv[CT];
    #pragma unroll
    for (int tt = 0; tt < CT; tt++) {
        int c = wc * (N / 4) + tt * 32 + cl;
        bb[tt] = bias[c];
        gv[tt] = g[c];
    }
    float ssm[16];
    #pragma unroll
    for (int m = 0; m < 16; m++) ssm[m] = 0.f;
    #pragma unroll
    for (int tt = 0; tt < CT; tt++)
        #pragma unroll
        for (int m = 0; m < 16; m++) {
            float v = fmaf(acc[tt][m], INV, bb[tt]);
            v = v > 0.f ? v : 0.f;
            acc[tt][m] = v;
            ssm[m] = fmaf(v, v, ssm[m]);
        }
    #pragma unroll
    for (int mask = 1; mask < 32; mask <<= 1)
        #pragma unroll
        for (int m = 0; m < 16; m++) ssm[m] += __shfl_xor(ssm[m], mask, 64);
    if (cl == 0) {
        #pragma unroll
        for (int m = 0; m < 16; m++) {
            int rl = wr * 32 + (m & 3) + 8 * (m >> 2) + 4 * g32;
            ssbuf[rl][wc] = ssm[m];
        }
    }
    __syncthreads();
    #pragma unroll
    for (int m = 0; m < 16; m++) {
        int rl = wr * 32 + (m & 3) + 8 * (m >> 2) + 4 * g32;
        float s4 = (ssbuf[rl][0] + ssbuf[rl][1]) + (ssbuf[rl][2] + ssbuf[rl][3]);
        float sc = 1.0f / sqrtf(s4 * (1.0f / (float)N) + 1e-6f);
        #pragma unroll
        for (int tt = 0; tt < CT; tt++) {
            int c = wc * (N / 4) + tt * 32 + cl;
            out[(size_t)(row0 + rl) * N + c] = acc[tt][m] * sc * gv[tt];
        }
    }
}

// ---------------- final MFMA Linear (512->768) + recon loss ----------------
// v2: same product-major COMPUTE reorder (CT=2)
__global__ __launch_bounds__(512, 2) void k_mfma_dec2(
    const float* __restrict__ A, const _Float16* __restrict__ Wt,
    const float* __restrict__ bias, float* __restrict__ rec,
    float* __restrict__ loss_acc, int K) {
    constexpr int NT = 256, NF = 768, CT = 2;
    __shared__ __align__(16) _Float16 Bs[2][NT * 64];
    __shared__ float red[8];
    const int tid = threadIdx.x;
    const int w = tid >> 6, lane = tid & 63;
    const int wr = w >> 2, wc = w & 3;
    const int g32 = lane >> 5, cl = lane & 31;
    const int row0 = blockIdx.x * 64;
    const int col0 = blockIdx.y * NT;
    const int NC = K >> 5;

    const float* ap = A + (size_t)(row0 + wr * 32 + cl) * K + g32 * 8;

    f32x16 acc[CT];
    #pragma unroll
    for (int tt = 0; tt < CT; tt++)
        #pragma unroll
        for (int m = 0; m < 16; m++) acc[tt][m] = 0.f;

    float4 Ar0[4], Ar1[4];

    auto STAGE = [&](int ch, int b) {
        #pragma unroll
        for (int p = 0; p < 4; p++) {
            int f = tid + 512 * p;
            int s = f >> 8, cloc = f & 255;
            const _Float16* gp = Wt + ((size_t)(ch * 8 + s) * NF + col0 + cloc) * 8;
            __builtin_amdgcn_global_load_lds(
                (const __attribute__((address_space(1))) void*)gp,
                (__attribute__((address_space(3))) void*)(&Bs[b][(size_t)f * 8]),
                16, 0, 0);
        }
    };
    auto AISSUE = [&](int ch, float4* Ar) {
        const float* bsrc = ap + ch * 32;
        Ar[0] = *(const float4*)(bsrc);
        Ar[1] = *(const float4*)(bsrc + 4);
        Ar[2] = *(const float4*)(bsrc + 16);
        Ar[3] = *(const float4*)(bsrc + 20);
    };
    auto COMPUTE = [&](int b, const float4* Ar) {
        #pragma unroll
        for (int t = 0; t < 2; t++) {
            float vv[8] = {Ar[t * 2].x, Ar[t * 2].y, Ar[t * 2].z, Ar[t * 2].w,
                           Ar[t * 2 + 1].x, Ar[t * 2 + 1].y, Ar[t * 2 + 1].z, Ar[t * 2 + 1].w};
            f16x8 ah, al;
            #pragma unroll
            for (int j = 0; j < 8; j++) {
                float v = vv[j] * 16.f;
                _Float16 h = (_Float16)v;
                ah[j] = h;
                al[j] = (_Float16)(v - (float)h);
            }
            f16x8 bh[CT], bl[CT];
            #pragma unroll
            for (int tt = 0; tt < CT; tt++) {
                int c = wc * 64 + tt * 32 + cl;
                bh[tt] = *(const f16x8*)&Bs[b][((size_t)(t * 2 + g32) * NT + c) * 8];
                bl[tt] = *(const f16x8*)&Bs[b][((size_t)(4 + t * 2 + g32) * NT + c) * 8];
            }
            #pragma unroll
            for (int tt = 0; tt < CT; tt++)
                acc[tt] = __builtin_amdgcn_mfma_f32_32x32x16_f16(ah, bh[tt], acc[tt], 0, 0, 0);
            #pragma unroll
            for (int tt = 0; tt < CT; tt++)
                acc[tt] = __builtin_amdgcn_mfma_f32_32x32x16_f16(al, bh[tt], acc[tt], 0, 0, 0);
            #pragma unroll
            for (int tt = 0; tt < CT; tt++)
                acc[tt] = __builtin_amdgcn_mfma_f32_32x32x16_f16(ah, bl[tt], acc[tt], 0, 0, 0);
        }
    };

    AISSUE(0, Ar0);
    STAGE(0, 0);
    for (int ch = 0; ch < NC; ch += 2) {
        __syncthreads();
        STAGE(ch + 1, 1);
        AISSUE(ch + 1, Ar1);
        COMPUTE(0, Ar0);
        __syncthreads();
        if (ch + 2 < NC) { STAGE(ch + 2, 0); AISSUE(ch + 2, Ar0); }
        COMPUTE(1, Ar1);
    }

    constexpr float INV = 1.f / 4096.f;
    float lsum = 0.f;
    #pragma unroll
    for (int tt = 0; tt < CT; tt++) {
        int cg = col0 + wc * 64 + tt * 32 + cl;
        float bb = bias[cg];
        #pragma unroll
        for (int m = 0; m < 16; m++) {
            int rl = wr * 32 + (m & 3) + 8 * (m >> 2) + 4 * g32;
            float v = fmaf(acc[tt][m], INV, bb);
            size_t o = (size_t)(row0 + rl) * NF + cg;
            float e = v - rec[o];             // rec holds xn here
            lsum = fmaf(e, e, lsum);
            rec[o] = v;
        }
    }
    #pragma unroll
    for (int mask = 1; mask < 64; mask <<= 1) lsum += __shfl_xor(lsum, mask, 64);
    if (lane == 0) red[w] = lsum;
    __syncthreads();
    if (tid == 0) {
        float t = 0.f;
        #pragma unroll
        for (int i = 0; i < 8; i++) t += red[i];
        atomicAdd(loss_acc, t * (1.0f / ((float)NB * (float)DIN)));
    }
}

// ---------------- VQ: fp16 hi/lo split MFMA scores + partial argmin (v7) -----
// score = 4096||E||^2 + (-32 r)·(256 E)  (-2 folded into R scale)
// v7: DIRECT-FROM-L2 E reads — no LDS, no __syncthreads, zero barriers.
// v6's per-chunk lockstep (stage drain -> barrier -> compute -> barrier) was
// the binding constraint (~106us vs ~30us resource floors). Each fragment is
// a per-lane-contiguous 16B global load (32 lanes = one 512B segment) from
// the Esp granule layout; waves run fully independently, compiler pipelines
// load->vmcnt->MFMA per kc, ~8 waves/CU TLP. E traffic 4x (1GB/dispatch from
// L2 ~= 31us floor) traded for barrier-freedom. Same product set/order per
// chain as v6 (bitwise identical), same C-layout map, ascending scan,
// tie -> smaller index.
__global__ __launch_bounds__(256) void k_vq_argmin_mfma(
    const _Float16* __restrict__ Rsp, const _Float16* __restrict__ Esp,
    const float* __restrict__ cbnS,
    float* __restrict__ pbest, int* __restrict__ pidx) {
    const int tid = threadIdx.x;
    const int w = tid >> 6, lane = tid & 63;
    const int g = lane >> 5, cl31 = lane & 31;
    const int rt0 = blockIdx.x * 256 + w * 64;        // wave's 64 rows
    const int cbase = blockIdx.y * 512;

    f16x8 Rh0[8], Rl0[8], Rh1[8], Rl1[8];
    {
        const _Float16* rp0 = Rsp + (size_t)(rt0 + cl31) * 256 + g * 8;
        const _Float16* rp1 = rp0 + 32 * 256;
        #pragma unroll
        for (int kc = 0; kc < 8; kc++) {
            Rh0[kc] = *(const f16x8*)(rp0 + kc * 16);
            Rl0[kc] = *(const f16x8*)(rp0 + 128 + kc * 16);
            Rh1[kc] = *(const f16x8*)(rp1 + kc * 16);
            Rl1[kc] = *(const f16x8*)(rp1 + 128 + kc * 16);
        }
    }

    float best0 = 3.402823466e+38f, best1 = 3.402823466e+38f;
    int bidx0 = 0, bidx1 = 0;

    for (int ch = 0; ch < 8; ch++) {
        const int c0c = cbase + ch * 64;
        const _Float16* ep = Esp + (size_t)(blockIdx.y * 8 + ch) * 16384;
        #pragma unroll
        for (int st = 0; st < 2; st++) {
            const int cloc = st * 32 + cl31;
            float cnv[16];
            #pragma unroll
            for (int q = 0; q < 4; q++) {
                float4 v = *(const float4*)(cbnS + c0c + st * 32 + q * 8 + 4 * g);
                cnv[q * 4 + 0] = v.x; cnv[q * 4 + 1] = v.y;
                cnv[q * 4 + 2] = v.z; cnv[q * 4 + 3] = v.w;
            }
            f32x16 c00, c01, c10, c11;
            #pragma unroll
            for (int m = 0; m < 16; m++) { c00[m] = 0.f; c01[m] = 0.f; c10[m] = 0.f; c11[m] = 0.f; }
            __builtin_amdgcn_s_setprio(1);
            #pragma unroll
            for (int kc = 0; kc < 8; kc++) {
                int sh = kc * 2 + g;
                f16x8 eh = *(const f16x8*)(ep + (size_t)sh * 512 + cloc * 8);
                f16x8 el = *(const f16x8*)(ep + (size_t)(16 + sh) * 512 + cloc * 8);
                c00 = __builtin_amdgcn_mfma_f32_32x32x16_f16(eh, Rh0[kc], c00, 0, 0, 0);
                c01 = __builtin_amdgcn_mfma_f32_32x32x16_f16(eh, Rh1[kc], c01, 0, 0, 0);
                c10 = __builtin_amdgcn_mfma_f32_32x32x16_f16(eh, Rl0[kc], c10, 0, 0, 0);
                c00 = __builtin_amdgcn_mfma_f32_32x32x16_f16(el, Rh0[kc], c00, 0, 0, 0);
                c01 = __builtin_amdgcn_mfma_f32_32x32x16_f16(el, Rh1[kc], c01, 0, 0, 0);
                c11 = __builtin_amdgcn_mfma_f32_32x32x16_f16(eh, Rl1[kc], c11, 0, 0, 0);
            }
            __builtin_amdgcn_s_setprio(0);
            // running argmin (D-row m -> code c0c + st*32 + 4g + (m&3)+8*(m>>2))
            const int c0g = c0c + st * 32 + 4 * g;
            #pragma unroll
            for (int m = 0; m < 16; m++) {
                int c = c0g + ((m & 3) + 8 * (m >> 2));
                float s0 = (c00[m] + c10[m]) + cnv[m];
                float s1 = (c01[m] + c11[m]) + cnv[m];
                if (s0 < best0) { best0 = s0; bidx0 = c; }
                if (s1 < best1) { best1 = s1; bidx1 = c; }
            }
        }
    }

    // merge lane-halves (same row, complementary code sets); tie -> smaller idx
    {
        float ob = __shfl_xor(best0, 32, 64);
        int oi = __shfl_xor(bidx0, 32, 64);
        if (ob < best0 || (ob == best0 && oi < bidx0)) { best0 = ob; bidx0 = oi; }
        ob = __shfl_xor(best1, 32, 64);
        oi = __shfl_xor(bidx1, 32, 64);
        if (ob < best1 || (ob == best1 && oi < bidx1)) { best1 = ob; bidx1 = oi; }
    }
    if (lane < 32) {
        const int part = blockIdx.y;
        pbest[(size_t)part * NB + rt0 + cl31] = best0;
        pidx [(size_t)part * NB + rt0 + cl31] = bidx0;
        pbest[(size_t)part * NB + rt0 + 32 + cl31] = best1;
        pidx [(size_t)part * NB + rt0 + 32 + cl31] = bidx1;
    }
}

// merge the 16 strip-partials; tie -> smaller index
__global__ void k_vq_reduce(const float* __restrict__ pbest, const int* __restrict__ pidx,
                            int* __restrict__ idx_out, float* __restrict__ ids_f) {
    int row = blockIdx.x * 256 + threadIdx.x;
    float b = pbest[row];
    int bi = pidx[row];
    #pragma unroll
    for (int s = 1; s < 16; s++) {
        float ob = pbest[(size_t)s * NB + row];
        int oi = pidx[(size_t)s * NB + row];
        if (ob < b || (ob == b && oi < bi)) { b = ob; bi = oi; }
    }
    idx_out[row] = bi;
    ids_f[(size_t)row * 4] = (float)bi;
}

// gather + residual update + qsum + vq_loss partial (v2):
// 8 elem/thread, float4x2 + f16x8 vector traffic; NO atomics — per-block
// partial ||rv||^2 written to part[]; k_vq_acc sums all 4 x 1024 at the end.
__global__ void k_vq_update(const float* __restrict__ Rin, const int* __restrict__ idx,
                            const float* __restrict__ E, float* __restrict__ Rout,
                            float* __restrict__ qsum, float* __restrict__ part,
                            int firstq, _Float16* __restrict__ Rsp) {
    __shared__ float ps[4];
    int t = blockIdx.x * 256 + threadIdx.x;   // NB*128/8 threads
    int i0 = t * 8;
    int row = i0 >> 7, d0 = i0 & 127;
    const float* ep = E + (size_t)idx[row] * 128 + d0;
    float4 e0 = *(const float4*)ep, e1 = *(const float4*)(ep + 4);
    float4 r0 = *(const float4*)&Rin[i0], r1 = *(const float4*)&Rin[i0 + 4];
    float rv[8] = {r0.x - e0.x, r0.y - e0.y, r0.z - e0.z, r0.w - e0.w,
                   r1.x - e1.x, r1.y - e1.y, r1.z - e1.z, r1.w - e1.w};
    *(float4*)&Rout[i0]     = make_float4(rv[0], rv[1], rv[2], rv[3]);
    *(float4*)&Rout[i0 + 4] = make_float4(rv[4], rv[5], rv[6], rv[7]);
    if (firstq) {
        *(float4*)&qsum[i0] = e0;
        *(float4*)&qsum[i0 + 4] = e1;
    } else {
        float4 q0 = *(const float4*)&qsum[i0], q1 = *(const float4*)&qsum[i0 + 4];
        *(float4*)&qsum[i0]     = make_float4(q0.x + e0.x, q0.y + e0.y, q0.z + e0.z, q0.w + e0.w);
        *(float4*)&qsum[i0 + 4] = make_float4(q1.x + e1.x, q1.y + e1.y, q1.z + e1.z, q1.w + e1.w);
    }
    f16x8 hi, lo;
    float p = 0.f;
    #pragma unroll
    for (int j = 0; j < 8; j++) {
        float rs = rv[j] * -32.f;
        _Float16 h = (_Float16)rs;
        hi[j] = h;
        lo[j] = (_Float16)(rs - (float)h);
        p = fmaf(rv[j], rv[j], p);
    }
    *(f16x8*)&Rsp[(size_t)row * 256 + d0] = hi;
    *(f16x8*)&Rsp[(size_t)row * 256 + 128 + d0] = lo;
    #pragma unroll
    for (int m = 1; m < 64; m <<= 1) p += __shfl_xor(p, m, 64);
    int lane = threadIdx.x & 63, wv = threadIdx.x >> 6;
    if (lane == 0) ps[wv] = p;
    __syncthreads();
    if (threadIdx.x == 0)
        part[blockIdx.x] = (ps[0] + ps[1]) + (ps[2] + ps[3]);
}

// sum the 4*1024 per-block partials into the vq_loss scalar (single writer)
__global__ void k_vq_acc(const float* __restrict__ part, float* __restrict__ vl) {
    __shared__ float ps[4];
    float s = 0.f;
    for (int i = threadIdx.x; i < 4096; i += 256) s += part[i];
    #pragma unroll
    for (int m = 1; m < 64; m <<= 1) s += __shfl_xor(s, m, 64);
    int lane = threadIdx.x & 63, wv = threadIdx.x >> 6;
    if (lane == 0) ps[wv] = s;
    __syncthreads();
    if (threadIdx.x == 0)
        *vl = ((ps[0] + ps[1]) + (ps[2] + ps[3])) * (1.25f / ((float)NB * 128.f));
}

// ---------------- launch ----------------

extern "C" void kernel_launch(void* const* d_in, const int* in_sizes, int n_in,
                              void* d_out, int out_size, void* d_ws, size_t ws_size,
                              hipStream_t stream) {
    (void)in_sizes; (void)n_in; (void)out_size; (void)ws_size;
    const float* x        = (const float*)d_in[0];
    const float* emb_mean = (const float*)d_in[1];
    const float* emb_std  = (const float*)d_in[2];
    const float* enc_w0 = (const float*)d_in[3];
    const float* enc_b0 = (const float*)d_in[4];
    const float* enc_g0 = (const float*)d_in[5];
    const float* enc_w1 = (const float*)d_in[6];
    const float* enc_b1 = (const float*)d_in[7];
    const float* enc_g1 = (const float*)d_in[8];
    const float* enc_w2 = (const float*)d_in[9];
    const float* enc_b2 = (const float*)d_in[10];
    const float* enc_g2 = (const float*)d_in[11];
    const float* cb     = (const float*)d_in[12];
    const float* dec_w0 = (const float*)d_in[13];
    const float* dec_b0 = (const float*)d_in[14];
    const float* dec_g0 = (const float*)d_in[15];
    const float* dec_w1 = (const float*)d_in[16];
    const float* dec_b1 = (const float*)d_in[17];
    const float* dec_g1 = (const float*)d_in[18];
    const float* dec_w2 = (const float*)d_in[19];
    const float* dec_b2 = (const float*)d_in[20];

    float* out   = (float*)d_out;
    float* xn    = out;                        // recon region doubles as xn scratch
    float* ids_f = out + (size_t)NB * DIN;
    float* rl    = out + (size_t)NB * DIN + (size_t)NB * 4;
    float* vl    = rl + 1;

    float* ws   = (float*)d_ws;
    float* h0   = ws;                           // 16384*512
    float* h1   = h0 + (size_t)NB * 512;        // 16384*256
    float* h2   = h1 + (size_t)NB * 256;        // 16384*128
    float* rbuf = h2 + (size_t)NB * 128;        // 16384*128
    float* qsum = rbuf + (size_t)NB * 128;      // 16384*128
    float* cbn  = qsum + (size_t)NB * 128;      // 4*8192
    int*   idxb = (int*)(cbn + 4 * 8192);       // 16384
    float* vqp  = (float*)(idxb + NB);          // 4*1024 loss partials

    // VQ scratch in h0 (free between enc1-read and dec1-write):
    float*    pbest = h0;                                   // 16*16384
    int*      pidx  = (int*)(h0 + 16 * (size_t)NB);         // 16*16384
    _Float16* Rsp   = (_Float16*)(h0 + 32 * (size_t)NB);
    _Float16* Esp   = (_Float16*)(h0 + 32 * (size_t)NB + (size_t)NB * 128);

    // weight splits live in rbuf: enc set dead before VQ writes rbuf (q=0
    // update); dec set written after the last vq_update reads rbuf.
    _Float16* WtE0 = (_Float16*)rbuf;           // 768*512*2 = 786432 halfs
    _Float16* WtE1 = WtE0 + 786432;             // 512*256*2 = 262144
    _Float16* WtE2 = WtE0 + 1048576;            // 256*128*2 =  65536
    _Float16* WtD0 = (_Float16*)rbuf;           // 128*256*2 =  65536
    _Float16* WtD1 = WtD0 + 65536;              // 256*512*2 = 262144
    _Float16* WtD2 = WtD0 + 327680;             // 512*768*2 = 786432

    k_zero2<<<1, 64, 0, stream>>>(rl, vl);
    k_norm<<<(NB * DIN) / 256, 256, 0, stream>>>(x, emb_mean, emb_std, xn);
    k_cbnorm<<<(4 * 8192) / 4, 256, 0, stream>>>(cb, cbn);

    k_wsplit<<<(768 * 512) / 256, 256, 0, stream>>>(enc_w0, WtE0, 768, 512);
    k_wsplit<<<(512 * 256) / 256, 256, 0, stream>>>(enc_w1, WtE1, 512, 256);
    k_wsplit<<<(256 * 128) / 256, 256, 0, stream>>>(enc_w2, WtE2, 256, 128);

    k_mfma_rms<512><<<NB / 64, 512, 0, stream>>>(xn, WtE0, enc_b0, enc_g0, h0, 768);
    k_mfma_rms<256><<<NB / 64, 512, 0, stream>>>(h0, WtE1, enc_b1, enc_g1, h1, 512);
    k_mfma_rms<128><<<NB / 64, 512, 0, stream>>>(h1, WtE2, enc_b2, enc_g2, h2, 256);

    // fp16 splits for VQ (into h0 region, after enc1 consumed h0)
    k_esplit<<<(4 * 8192 * 128) / 256, 256, 0, stream>>>(cb, Esp);
    k_split<<<(NB * 128) / 256, 256, 0, stream>>>(h2, Rsp, -32.f);

    for (int q = 0; q < 4; q++) {
        const float* R = (q == 0) ? h2 : rbuf;
        const float* Eq = cb + (size_t)q * 8192 * 128;
        const _Float16* EspQ = Esp + (size_t)q * 2097152;
        dim3 gq(NB / 256, 16);
        k_vq_argmin_mfma<<<gq, 256, 0, stream>>>(Rsp, EspQ, cbn + q * 8192, pbest, pidx);
        k_vq_reduce<<<NB / 256, 256, 0, stream>>>(pbest, pidx, idxb, ids_f + q);
        k_vq_update<<<(NB * 128) / 2048, 256, 0, stream>>>(R, idxb, Eq, rbuf, qsum,
                                                           vqp + q * 1024, q == 0 ? 1 : 0, Rsp);
    }
    k_vq_acc<<<1, 256, 0, stream>>>(vqp, vl);

    // dec weight splits (rbuf dead after last vq_update)
    k_wsplit<<<(128 * 256) / 256, 256, 0, stream>>>(dec_w0, WtD0, 128, 256);
    k_wsplit<<<(256 * 512) / 256, 256, 0, stream>>>(dec_w1, WtD1, 256, 512);
    k_wsplit<<<(512 * 768) / 256, 256, 0, stream>>>(dec_w2, WtD2, 512, 768);

    k_mfma_rms<256><<<NB / 64, 512, 0, stream>>>(qsum, WtD0, dec_b0, dec_g0, h1, 128);
    k_mfma_rms<512><<<NB / 64, 512, 0, stream>>>(h1, WtD1, dec_b1, dec_g1, h0, 256);

    dim3 g2(NB / 64, 3);
    k_mfma_dec2<<<g2, 512, 0, stream>>>(h0, WtD2, dec_b2, xn, rl, 512);
}

// Round 10
// 858.377 us; speedup vs baseline: 1.5032x; 1.5032x over previous
//
#include <hip/hip_runtime.h>
#include <math.h>

#define NB 16384
#define DIN 768

typedef _Float16 f16x8 __attribute__((ext_vector_type(8)));
typedef float f32x16 __attribute__((ext_vector_type(16)));

// ---------------- small kernels ----------------

// also zeroes the recon-loss accumulator (rl) -> k_zero2 launch removed
__global__ void k_norm(const float* __restrict__ x, const float* __restrict__ m,
                       const float* __restrict__ s, float* __restrict__ xn,
                       float* __restrict__ rl) {
    int i = blockIdx.x * 256 + threadIdx.x;          // 16384*768 total
    int j = i % DIN;
    xn[i] = (x[i] - m[j]) / s[j];
    if (i == 0) *rl = 0.f;
}

// one 64-lane wave per codebook row; writes ||E||^2 * 4096 (r*-32, E*256 scaling)
__global__ void k_cbnorm(const float* __restrict__ cb, float* __restrict__ cbn) {
    int row = blockIdx.x * 4 + (threadIdx.x >> 6);
    int lane = threadIdx.x & 63;
    const float* p = cb + (size_t)row * 128;
    float v0 = p[lane], v1 = p[lane + 64];
    float s = v0 * v0 + v1 * v1;
    #pragma unroll
    for (int m = 32; m >= 1; m >>= 1) s += __shfl_xor(s, m, 64);
    if (lane == 0) cbn[row] = s * 4096.f;
}

// split fp32 rows (n x 128) into fp16 hi|lo layout (n x 256): [hi(128) | lo(128)]
__global__ void k_split(const float* __restrict__ src, _Float16* __restrict__ dst,
                        float scale) {
    int i = blockIdx.x * 256 + threadIdx.x;   // n*128 elements
    int row = i >> 7, d = i & 127;
    float v = src[i] * scale;
    _Float16 hi = (_Float16)v;
    dst[(size_t)row * 256 + d] = hi;
    dst[(size_t)row * 256 + 128 + d] = (_Float16)(v - (float)hi);
}

// E split into per-chunk granule layout (64-code chunks): chunk ch = c>>6;
// halfs offset = q*2097152 + ch*16384 + slice*512 + (c&63)*8 + (k&7)
// slice = k>>3 (hi) / 16 + (k>>3) (lo). Scale 256.
__global__ void k_esplit(const float* __restrict__ cb, _Float16* __restrict__ Esp) {
    int i = blockIdx.x * 256 + threadIdx.x;   // 4*8192*128 total
    int q = i >> 20;
    int rem = i & 1048575;
    int c = rem >> 7, k = rem & 127;
    float v = cb[i] * 256.f;
    _Float16 hi = (_Float16)v;
    _Float16 lo = (_Float16)(v - (float)hi);
    int sh = k >> 3, j = k & 7;
    size_t base = (size_t)q * 2097152 + (size_t)(c >> 6) * 16384 + (size_t)(c & 63) * 8 + j;
    Esp[base + (size_t)sh * 512] = hi;
    Esp[base + (size_t)(16 + sh) * 512] = lo;
}

// ---------------- weight transpose-split into chunked granule layout ----------
// W (K x N fp32) -> Wt halfs, granule (kc, s, c): ((kc*8+s)*N + c)*8 + j
// k = kc*32 + t*16 + g*8 + j ; s = t*2+g (hi), 4+t*2+g (lo). Scale 256.
__global__ void k_wsplit(const float* __restrict__ W, _Float16* __restrict__ Wt,
                         int K, int N) {
    int i = blockIdx.x * 256 + threadIdx.x;   // K*N total
    int k = i / N, c = i - k * N;
    float v = W[i] * 256.f;
    _Float16 hi = (_Float16)v;
    _Float16 lo = (_Float16)(v - (float)hi);
    int kc = k >> 5, kin = k & 31;
    int t = kin >> 4, gg = (kin >> 3) & 1, j = kin & 7;
    size_t base = ((size_t)(kc * 8) * N + c) * 8 + j;
    Wt[base + (size_t)(t * 2 + gg) * N * 8] = hi;
    Wt[base + (size_t)(4 + t * 2 + gg) * N * 8] = lo;
}

// ---------------- fused MFMA Linear + ReLU + RMSNorm ----------------
// v2: COMPUTE product-major (tt inner), bitwise identical accumulation order.
template <int N>
__global__ __launch_bounds__(512, 2) void k_mfma_rms(
    const float* __restrict__ A, const _Float16* __restrict__ Wt,
    const float* __restrict__ bias, const float* __restrict__ g,
    float* __restrict__ out, int K) {
    constexpr int CT = N / 128;               // col-tiles per wave
    __shared__ __align__(16) _Float16 Bs[2][N * 64];
    __shared__ float ssbuf[64][4];
    const int tid = threadIdx.x;
    const int w = tid >> 6, lane = tid & 63;
    const int wr = w >> 2, wc = w & 3;
    const int g32 = lane >> 5, cl = lane & 31;
    const int row0 = blockIdx.x * 64;
    const int NC = K >> 5;                    // chunks of 32 k (always even)

    const float* ap = A + (size_t)(row0 + wr * 32 + cl) * K + g32 * 8;

    f32x16 acc[CT];
    #pragma unroll
    for (int tt = 0; tt < CT; tt++)
        #pragma unroll
        for (int m = 0; m < 16; m++) acc[tt][m] = 0.f;

    float4 Ar0[4], Ar1[4];

    auto STAGE = [&](int ch, int b) {
        const _Float16* gp = Wt + (size_t)ch * 8 * N * 8;
        #pragma unroll
        for (int p = 0; p < N / 64; p++) {
            int f = tid + 512 * p;
            __builtin_amdgcn_global_load_lds(
                (const __attribute__((address_space(1))) void*)(gp + (size_t)f * 8),
                (__attribute__((address_space(3))) void*)(&Bs[b][(size_t)f * 8]),
                16, 0, 0);
        }
    };
    auto AISSUE = [&](int ch, float4* Ar) {
        const float* bsrc = ap + ch * 32;
        Ar[0] = *(const float4*)(bsrc);
        Ar[1] = *(const float4*)(bsrc + 4);
        Ar[2] = *(const float4*)(bsrc + 16);
        Ar[3] = *(const float4*)(bsrc + 20);
    };
    auto COMPUTE = [&](int b, const float4* Ar) {
        #pragma unroll
        for (int t = 0; t < 2; t++) {
            float vv[8] = {Ar[t * 2].x, Ar[t * 2].y, Ar[t * 2].z, Ar[t * 2].w,
                           Ar[t * 2 + 1].x, Ar[t * 2 + 1].y, Ar[t * 2 + 1].z, Ar[t * 2 + 1].w};
            f16x8 ah, al;
            #pragma unroll
            for (int j = 0; j < 8; j++) {
                float v = vv[j] * 16.f;
                _Float16 h = (_Float16)v;
                ah[j] = h;
                al[j] = (_Float16)(v - (float)h);
            }
            f16x8 bh[CT], bl[CT];
            #pragma unroll
            for (int tt = 0; tt < CT; tt++) {
                int c = wc * (N / 4) + tt * 32 + cl;
                bh[tt] = *(const f16x8*)&Bs[b][((size_t)(t * 2 + g32) * N + c) * 8];
                bl[tt] = *(const f16x8*)&Bs[b][((size_t)(4 + t * 2 + g32) * N + c) * 8];
            }
            #pragma unroll
            for (int tt = 0; tt < CT; tt++)
                acc[tt] = __builtin_amdgcn_mfma_f32_32x32x16_f16(ah, bh[tt], acc[tt], 0, 0, 0);
            #pragma unroll
            for (int tt = 0; tt < CT; tt++)
                acc[tt] = __builtin_amdgcn_mfma_f32_32x32x16_f16(al, bh[tt], acc[tt], 0, 0, 0);
            #pragma unroll
            for (int tt = 0; tt < CT; tt++)
                acc[tt] = __builtin_amdgcn_mfma_f32_32x32x16_f16(ah, bl[tt], acc[tt], 0, 0, 0);
        }
    };

    AISSUE(0, Ar0);
    STAGE(0, 0);
    for (int ch = 0; ch < NC; ch += 2) {
        __syncthreads();                      // drains stage(ch) + A loads
        STAGE(ch + 1, 1);
        AISSUE(ch + 1, Ar1);
        COMPUTE(0, Ar0);
        __syncthreads();                      // drains stage(ch+1)
        if (ch + 2 < NC) { STAGE(ch + 2, 0); AISSUE(ch + 2, Ar0); }
        COMPUTE(1, Ar1);
    }

    // epilogue: /4096 + bias + relu + rmsnorm
    constexpr float INV = 1.f / 4096.f;
    float bb[CT], gv[CT];
    #pragma unroll
    for (int tt = 0; tt < CT; tt++) {
        int c = wc * (N / 4) + tt * 32 + cl;
        bb[tt] = bias[c];
        gv[tt] = g[c];
    }
    float ssm[16];
    #pragma unroll
    for (int m = 0; m < 16; m++) ssm[m] = 0.f;
    #pragma unroll
    for (int tt = 0; tt < CT; tt++)
        #pragma unroll
        for (int m = 0; m < 16; m++) {
            float v = fmaf(acc[tt][m], INV, bb[tt]);
            v = v > 0.f ? v : 0.f;
            acc[tt][m] = v;
            ssm[m] = fmaf(v, v, ssm[m]);
        }
    #pragma unroll
    for (int mask = 1; mask < 32; mask <<= 1)
        #pragma unroll
        for (int m = 0; m < 16; m++) ssm[m] += __shfl_xor(ssm[m], mask, 64);
    if (cl == 0) {
        #pragma unroll
        for (int m = 0; m < 16; m++) {
            int rl = wr * 32 + (m & 3) + 8 * (m >> 2) + 4 * g32;
            ssbuf[rl][wc] = ssm[m];
        }
    }
    __syncthreads();
    #pragma unroll
    for (int m = 0; m < 16; m++) {
        int rl = wr * 32 + (m & 3) + 8 * (m >> 2) + 4 * g32;
        float s4 = (ssbuf[rl][0] + ssbuf[rl][1]) + (ssbuf[rl][2] + ssbuf[rl][3]);
        float sc = 1.0f / sqrtf(s4 * (1.0f / (float)N) + 1e-6f);
        #pragma unroll
        for (int tt = 0; tt < CT; tt++) {
            int c = wc * (N / 4) + tt * 32 + cl;
            out[(size_t)(row0 + rl) * N + c] = acc[tt][m] * sc * gv[tt];
        }
    }
}

// ---------------- final MFMA Linear (512->768) + recon loss ----------------
// v2: same product-major COMPUTE reorder (CT=2)
__global__ __launch_bounds__(512, 2) void k_mfma_dec2(
    const float* __restrict__ A, const _Float16* __restrict__ Wt,
    const float* __restrict__ bias, float* __restrict__ rec,
    float* __restrict__ loss_acc, int K) {
    constexpr int NT = 256, NF = 768, CT = 2;
    __shared__ __align__(16) _Float16 Bs[2][NT * 64];
    __shared__ float red[8];
    const int tid = threadIdx.x;
    const int w = tid >> 6, lane = tid & 63;
    const int wr = w >> 2, wc = w & 3;
    const int g32 = lane >> 5, cl = lane & 31;
    const int row0 = blockIdx.x * 64;
    const int col0 = blockIdx.y * NT;
    const int NC = K >> 5;

    const float* ap = A + (size_t)(row0 + wr * 32 + cl) * K + g32 * 8;

    f32x16 acc[CT];
    #pragma unroll
    for (int tt = 0; tt < CT; tt++)
        #pragma unroll
        for (int m = 0; m < 16; m++) acc[tt][m] = 0.f;

    float4 Ar0[4], Ar1[4];

    auto STAGE = [&](int ch, int b) {
        #pragma unroll
        for (int p = 0; p < 4; p++) {
            int f = tid + 512 * p;
            int s = f >> 8, cloc = f & 255;
            const _Float16* gp = Wt + ((size_t)(ch * 8 + s) * NF + col0 + cloc) * 8;
            __builtin_amdgcn_global_load_lds(
                (const __attribute__((address_space(1))) void*)gp,
                (__attribute__((address_space(3))) void*)(&Bs[b][(size_t)f * 8]),
                16, 0, 0);
        }
    };
    auto AISSUE = [&](int ch, float4* Ar) {
        const float* bsrc = ap + ch * 32;
        Ar[0] = *(const float4*)(bsrc);
        Ar[1] = *(const float4*)(bsrc + 4);
        Ar[2] = *(const float4*)(bsrc + 16);
        Ar[3] = *(const float4*)(bsrc + 20);
    };
    auto COMPUTE = [&](int b, const float4* Ar) {
        #pragma unroll
        for (int t = 0; t < 2; t++) {
            float vv[8] = {Ar[t * 2].x, Ar[t * 2].y, Ar[t * 2].z, Ar[t * 2].w,
                           Ar[t * 2 + 1].x, Ar[t * 2 + 1].y, Ar[t * 2 + 1].z, Ar[t * 2 + 1].w};
            f16x8 ah, al;
            #pragma unroll
            for (int j = 0; j < 8; j++) {
                float v = vv[j] * 16.f;
                _Float16 h = (_Float16)v;
                ah[j] = h;
                al[j] = (_Float16)(v - (float)h);
            }
            f16x8 bh[CT], bl[CT];
            #pragma unroll
            for (int tt = 0; tt < CT; tt++) {
                int c = wc * 64 + tt * 32 + cl;
                bh[tt] = *(const f16x8*)&Bs[b][((size_t)(t * 2 + g32) * NT + c) * 8];
                bl[tt] = *(const f16x8*)&Bs[b][((size_t)(4 + t * 2 + g32) * NT + c) * 8];
            }
            #pragma unroll
            for (int tt = 0; tt < CT; tt++)
                acc[tt] = __builtin_amdgcn_mfma_f32_32x32x16_f16(ah, bh[tt], acc[tt], 0, 0, 0);
            #pragma unroll
            for (int tt = 0; tt < CT; tt++)
                acc[tt] = __builtin_amdgcn_mfma_f32_32x32x16_f16(al, bh[tt], acc[tt], 0, 0, 0);
            #pragma unroll
            for (int tt = 0; tt < CT; tt++)
                acc[tt] = __builtin_amdgcn_mfma_f32_32x32x16_f16(ah, bl[tt], acc[tt], 0, 0, 0);
        }
    };

    AISSUE(0, Ar0);
    STAGE(0, 0);
    for (int ch = 0; ch < NC; ch += 2) {
        __syncthreads();
        STAGE(ch + 1, 1);
        AISSUE(ch + 1, Ar1);
        COMPUTE(0, Ar0);
        __syncthreads();
        if (ch + 2 < NC) { STAGE(ch + 2, 0); AISSUE(ch + 2, Ar0); }
        COMPUTE(1, Ar1);
    }

    constexpr float INV = 1.f / 4096.f;
    float lsum = 0.f;
    #pragma unroll
    for (int tt = 0; tt < CT; tt++) {
        int cg = col0 + wc * 64 + tt * 32 + cl;
        float bb = bias[cg];
        #pragma unroll
        for (int m = 0; m < 16; m++) {
            int rl = wr * 32 + (m & 3) + 8 * (m >> 2) + 4 * g32;
            float v = fmaf(acc[tt][m], INV, bb);
            size_t o = (size_t)(row0 + rl) * NF + cg;
            float e = v - rec[o];             // rec holds xn here
            lsum = fmaf(e, e, lsum);
            rec[o] = v;
        }
    }
    #pragma unroll
    for (int mask = 1; mask < 64; mask <<= 1) lsum += __shfl_xor(lsum, mask, 64);
    if (lane == 0) red[w] = lsum;
    __syncthreads();
    if (tid == 0) {
        float t = 0.f;
        #pragma unroll
        for (int i = 0; i < 8; i++) t += red[i];
        atomicAdd(loss_acc, t * (1.0f / ((float)NB * (float)DIN)));
    }
}

// ---------------- VQ: fp16 hi/lo split MFMA scores + partial argmin (v6) -----
// REVERTED to the round-8-verified v6 (106us steady): LDS double-buffered
// 64-code chunks, 4 chains, d=3 round-robin. v7 (direct-L2, no barriers)
// regressed to 210us: occupancy 11% + per-kc L2 latency exposure.
__global__ __launch_bounds__(256, 2) void k_vq_argmin_mfma(
    const _Float16* __restrict__ Rsp, const _Float16* __restrict__ Esp,
    const float* __restrict__ cbnS,
    float* __restrict__ pbest, int* __restrict__ pidx) {
    __shared__ __align__(16) _Float16 Es[2][16384];   // 2 x 32KB (64 codes each)
    const int tid = threadIdx.x;
    const int w = tid >> 6, lane = tid & 63;
    const int g = lane >> 5, cl31 = lane & 31;
    const int rt0 = blockIdx.x * 256 + w * 64;        // wave's 64 rows
    const int cbase = blockIdx.y * 512;
    const int ch0 = blockIdx.y * 8;

    f16x8 Rh0[8], Rl0[8], Rh1[8], Rl1[8];
    {
        const _Float16* rp0 = Rsp + (size_t)(rt0 + cl31) * 256 + g * 8;
        const _Float16* rp1 = rp0 + 32 * 256;
        #pragma unroll
        for (int kc = 0; kc < 8; kc++) {
            Rh0[kc] = *(const f16x8*)(rp0 + kc * 16);
            Rl0[kc] = *(const f16x8*)(rp0 + 128 + kc * 16);
            Rh1[kc] = *(const f16x8*)(rp1 + kc * 16);
            Rl1[kc] = *(const f16x8*)(rp1 + 128 + kc * 16);
        }
    }

    float best0 = 3.402823466e+38f, best1 = 3.402823466e+38f;
    int bidx0 = 0, bidx1 = 0;

    auto STAGE = [&](int gch, int b) {
        const _Float16* gp = Esp + (size_t)gch * 16384;
        #pragma unroll
        for (int p = 0; p < 8; p++) {
            int f = tid + 256 * p;
            __builtin_amdgcn_global_load_lds(
                (const __attribute__((address_space(1))) void*)(gp + (size_t)f * 8),
                (__attribute__((address_space(3))) void*)(&Es[b][(size_t)f * 8]),
                16, 0, 0);
        }
    };

    STAGE(ch0, 0);
    for (int ch = 0; ch < 8; ch++) {
        const int buf = ch & 1;
        const int c0c = cbase + ch * 64;
        // cbn for both 32-code subtiles, loaded BEFORE the barrier
        float cnv0[16], cnv1[16];
        #pragma unroll
        for (int q = 0; q < 4; q++) {
            float4 v0 = *(const float4*)(cbnS + c0c + q * 8 + 4 * g);
            float4 v1 = *(const float4*)(cbnS + c0c + 32 + q * 8 + 4 * g);
            cnv0[q * 4 + 0] = v0.x; cnv0[q * 4 + 1] = v0.y;
            cnv0[q * 4 + 2] = v0.z; cnv0[q * 4 + 3] = v0.w;
            cnv1[q * 4 + 0] = v1.x; cnv1[q * 4 + 1] = v1.y;
            cnv1[q * 4 + 2] = v1.z; cnv1[q * 4 + 3] = v1.w;
        }
        __syncthreads();                      // stage(ch) landed; buf readable
        if (ch < 7) STAGE(ch0 + ch + 1, buf ^ 1);
        #pragma unroll
        for (int st = 0; st < 2; st++) {
            const int cloc = st * 32 + cl31;
            const float* cnv = st ? cnv1 : cnv0;
            f32x16 c00, c01, c10, c11;
            #pragma unroll
            for (int m = 0; m < 16; m++) { c00[m] = 0.f; c01[m] = 0.f; c10[m] = 0.f; c11[m] = 0.f; }
            __builtin_amdgcn_s_setprio(1);
            #pragma unroll
            for (int kc = 0; kc < 8; kc++) {
                int sh = kc * 2 + g;
                f16x8 eh = *(const f16x8*)&Es[buf][sh * 512 + cloc * 8];
                f16x8 el = *(const f16x8*)&Es[buf][(16 + sh) * 512 + cloc * 8];
                c00 = __builtin_amdgcn_mfma_f32_32x32x16_f16(eh, Rh0[kc], c00, 0, 0, 0);
                c01 = __builtin_amdgcn_mfma_f32_32x32x16_f16(eh, Rh1[kc], c01, 0, 0, 0);
                c10 = __builtin_amdgcn_mfma_f32_32x32x16_f16(eh, Rl0[kc], c10, 0, 0, 0);
                c00 = __builtin_amdgcn_mfma_f32_32x32x16_f16(el, Rh0[kc], c00, 0, 0, 0);
                c01 = __builtin_amdgcn_mfma_f32_32x32x16_f16(el, Rh1[kc], c01, 0, 0, 0);
                c11 = __builtin_amdgcn_mfma_f32_32x32x16_f16(eh, Rl1[kc], c11, 0, 0, 0);
            }
            __builtin_amdgcn_s_setprio(0);
            // running argmin (D-row m -> code c0c + st*32 + 4g + (m&3)+8*(m>>2))
            const int c0g = c0c + st * 32 + 4 * g;
            #pragma unroll
            for (int m = 0; m < 16; m++) {
                int c = c0g + ((m & 3) + 8 * (m >> 2));
                float s0 = (c00[m] + c10[m]) + cnv[m];
                float s1 = (c01[m] + c11[m]) + cnv[m];
                if (s0 < best0) { best0 = s0; bidx0 = c; }
                if (s1 < best1) { best1 = s1; bidx1 = c; }
            }
        }
    }

    // merge lane-halves (same row, complementary code sets); tie -> smaller idx
    {
        float ob = __shfl_xor(best0, 32, 64);
        int oi = __shfl_xor(bidx0, 32, 64);
        if (ob < best0 || (ob == best0 && oi < bidx0)) { best0 = ob; bidx0 = oi; }
        ob = __shfl_xor(best1, 32, 64);
        oi = __shfl_xor(bidx1, 32, 64);
        if (ob < best1 || (ob == best1 && oi < bidx1)) { best1 = ob; bidx1 = oi; }
    }
    if (lane < 32) {
        const int part = blockIdx.y;
        pbest[(size_t)part * NB + rt0 + cl31] = best0;
        pidx [(size_t)part * NB + rt0 + cl31] = bidx0;
        pbest[(size_t)part * NB + rt0 + 32 + cl31] = best1;
        pidx [(size_t)part * NB + rt0 + 32 + cl31] = bidx1;
    }
}

// fused strip-merge + gather + residual update + qsum + vq_loss partial (v3):
// the 16-strip argmin merge is a 4-step shfl_xor over the 16 lanes owning one
// row (strip = lane&15; pbest layout [strip][row]); tie -> smaller index is
// associative so the butterfly is exact. Winning index feeds the gather
// directly (k_vq_reduce launch + idxb round-trip removed). 8 elem/thread,
// float4x2 + f16x8 vector traffic; NO atomics (per-block partial -> part[]).
__global__ void k_vq_update(const float* __restrict__ Rin,
                            const float* __restrict__ pbest, const int* __restrict__ pidx,
                            const float* __restrict__ E, float* __restrict__ Rout,
                            float* __restrict__ qsum, float* __restrict__ part,
                            int firstq, _Float16* __restrict__ Rsp,
                            float* __restrict__ ids_f) {
    __shared__ float ps[4];
    int t = blockIdx.x * 256 + threadIdx.x;   // NB*128/8 threads
    int i0 = t * 8;
    int row = i0 >> 7, d0 = i0 & 127;
    int lane = threadIdx.x & 63;
    // strip-merge: this thread owns strip s = lane&15 of its row
    float b = pbest[(size_t)(lane & 15) * NB + row];
    int bi = pidx[(size_t)(lane & 15) * NB + row];
    #pragma unroll
    for (int m = 1; m < 16; m <<= 1) {
        float ob = __shfl_xor(b, m, 64);
        int oi = __shfl_xor(bi, m, 64);
        if (ob < b || (ob == b && oi < bi)) { b = ob; bi = oi; }
    }
    if (d0 == 0) ids_f[(size_t)row * 4] = (float)bi;
    const float* ep = E + (size_t)bi * 128 + d0;
    float4 e0 = *(const float4*)ep, e1 = *(const float4*)(ep + 4);
    float4 r0 = *(const float4*)&Rin[i0], r1 = *(const float4*)&Rin[i0 + 4];
    float rv[8] = {r0.x - e0.x, r0.y - e0.y, r0.z - e0.z, r0.w - e0.w,
                   r1.x - e1.x, r1.y - e1.y, r1.z - e1.z, r1.w - e1.w};
    *(float4*)&Rout[i0]     = make_float4(rv[0], rv[1], rv[2], rv[3]);
    *(float4*)&Rout[i0 + 4] = make_float4(rv[4], rv[5], rv[6], rv[7]);
    if (firstq) {
        *(float4*)&qsum[i0] = e0;
        *(float4*)&qsum[i0 + 4] = e1;
    } else {
        float4 q0 = *(const float4*)&qsum[i0], q1 = *(const float4*)&qsum[i0 + 4];
        *(float4*)&qsum[i0]     = make_float4(q0.x + e0.x, q0.y + e0.y, q0.z + e0.z, q0.w + e0.w);
        *(float4*)&qsum[i0 + 4] = make_float4(q1.x + e1.x, q1.y + e1.y, q1.z + e1.z, q1.w + e1.w);
    }
    f16x8 hi, lo;
    float p = 0.f;
    #pragma unroll
    for (int j = 0; j < 8; j++) {
        float rs = rv[j] * -32.f;
        _Float16 h = (_Float16)rs;
        hi[j] = h;
        lo[j] = (_Float16)(rs - (float)h);
        p = fmaf(rv[j], rv[j], p);
    }
    *(f16x8*)&Rsp[(size_t)row * 256 + d0] = hi;
    *(f16x8*)&Rsp[(size_t)row * 256 + 128 + d0] = lo;
    #pragma unroll
    for (int m = 1; m < 64; m <<= 1) p += __shfl_xor(p, m, 64);
    int wv = threadIdx.x >> 6;
    if (lane == 0) ps[wv] = p;
    __syncthreads();
    if (threadIdx.x == 0)
        part[blockIdx.x] = (ps[0] + ps[1]) + (ps[2] + ps[3]);
}

// sum the 4*1024 per-block partials into the vq_loss scalar (single writer)
__global__ void k_vq_acc(const float* __restrict__ part, float* __restrict__ vl) {
    __shared__ float ps[4];
    float s = 0.f;
    for (int i = threadIdx.x; i < 4096; i += 256) s += part[i];
    #pragma unroll
    for (int m = 1; m < 64; m <<= 1) s += __shfl_xor(s, m, 64);
    int lane = threadIdx.x & 63, wv = threadIdx.x >> 6;
    if (lane == 0) ps[wv] = s;
    __syncthreads();
    if (threadIdx.x == 0)
        *vl = ((ps[0] + ps[1]) + (ps[2] + ps[3])) * (1.25f / ((float)NB * 128.f));
}

// ---------------- launch ----------------

extern "C" void kernel_launch(void* const* d_in, const int* in_sizes, int n_in,
                              void* d_out, int out_size, void* d_ws, size_t ws_size,
                              hipStream_t stream) {
    (void)in_sizes; (void)n_in; (void)out_size; (void)ws_size;
    const float* x        = (const float*)d_in[0];
    const float* emb_mean = (const float*)d_in[1];
    const float* emb_std  = (const float*)d_in[2];
    const float* enc_w0 = (const float*)d_in[3];
    const float* enc_b0 = (const float*)d_in[4];
    const float* enc_g0 = (const float*)d_in[5];
    const float* enc_w1 = (const float*)d_in[6];
    const float* enc_b1 = (const float*)d_in[7];
    const float* enc_g1 = (const float*)d_in[8];
    const float* enc_w2 = (const float*)d_in[9];
    const float* enc_b2 = (const float*)d_in[10];
    const float* enc_g2 = (const float*)d_in[11];
    const float* cb     = (const float*)d_in[12];
    const float* dec_w0 = (const float*)d_in[13];
    const float* dec_b0 = (const float*)d_in[14];
    const float* dec_g0 = (const float*)d_in[15];
    const float* dec_w1 = (const float*)d_in[16];
    const float* dec_b1 = (const float*)d_in[17];
    const float* dec_g1 = (const float*)d_in[18];
    const float* dec_w2 = (const float*)d_in[19];
    const float* dec_b2 = (const float*)d_in[20];

    float* out   = (float*)d_out;
    float* xn    = out;                        // recon region doubles as xn scratch
    float* ids_f = out + (size_t)NB * DIN;
    float* rl    = out + (size_t)NB * DIN + (size_t)NB * 4;
    float* vl    = rl + 1;

    float* ws   = (float*)d_ws;
    float* h0   = ws;                           // 16384*512
    float* h1   = h0 + (size_t)NB * 512;        // 16384*256
    float* h2   = h1 + (size_t)NB * 256;        // 16384*128
    float* rbuf = h2 + (size_t)NB * 128;        // 16384*128
    float* qsum = rbuf + (size_t)NB * 128;      // 16384*128
    float* cbn  = qsum + (size_t)NB * 128;      // 4*8192
    int*   idxb = (int*)(cbn + 4 * 8192);       // 16384 (unused, kept for layout)
    float* vqp  = (float*)(idxb + NB);          // 4*1024 loss partials

    // VQ scratch in h0 (free between enc1-read and dec1-write):
    float*    pbest = h0;                                   // 16*16384
    int*      pidx  = (int*)(h0 + 16 * (size_t)NB);         // 16*16384
    _Float16* Rsp   = (_Float16*)(h0 + 32 * (size_t)NB);
    _Float16* Esp   = (_Float16*)(h0 + 32 * (size_t)NB + (size_t)NB * 128);

    // weight splits live in rbuf: enc set dead before VQ writes rbuf (q=0
    // update); dec set written after the last vq_update reads rbuf.
    _Float16* WtE0 = (_Float16*)rbuf;           // 768*512*2 = 786432 halfs
    _Float16* WtE1 = WtE0 + 786432;             // 512*256*2 = 262144
    _Float16* WtE2 = WtE0 + 1048576;            // 256*128*2 =  65536
    _Float16* WtD0 = (_Float16*)rbuf;           // 128*256*2 =  65536
    _Float16* WtD1 = WtD0 + 65536;              // 256*512*2 = 262144
    _Float16* WtD2 = WtD0 + 327680;             // 512*768*2 = 786432

    k_norm<<<(NB * DIN) / 256, 256, 0, stream>>>(x, emb_mean, emb_std, xn, rl);
    k_cbnorm<<<(4 * 8192) / 4, 256, 0, stream>>>(cb, cbn);

    k_wsplit<<<(768 * 512) / 256, 256, 0, stream>>>(enc_w0, WtE0, 768, 512);
    k_wsplit<<<(512 * 256) / 256, 256, 0, stream>>>(enc_w1, WtE1, 512, 256);
    k_wsplit<<<(256 * 128) / 256, 256, 0, stream>>>(enc_w2, WtE2, 256, 128);

    k_mfma_rms<512><<<NB / 64, 512, 0, stream>>>(xn, WtE0, enc_b0, enc_g0, h0, 768);
    k_mfma_rms<256><<<NB / 64, 512, 0, stream>>>(h0, WtE1, enc_b1, enc_g1, h1, 512);
    k_mfma_rms<128><<<NB / 64, 512, 0, stream>>>(h1, WtE2, enc_b2, enc_g2, h2, 256);

    // fp16 splits for VQ (into h0 region, after enc1 consumed h0)
    k_esplit<<<(4 * 8192 * 128) / 256, 256, 0, stream>>>(cb, Esp);
    k_split<<<(NB * 128) / 256, 256, 0, stream>>>(h2, Rsp, -32.f);

    for (int q = 0; q < 4; q++) {
        const float* R = (q == 0) ? h2 : rbuf;
        const float* Eq = cb + (size_t)q * 8192 * 128;
        const _Float16* EspQ = Esp + (size_t)q * 2097152;
        dim3 gq(NB / 256, 16);
        k_vq_argmin_mfma<<<gq, 256, 0, stream>>>(Rsp, EspQ, cbn + q * 8192, pbest, pidx);
        k_vq_update<<<(NB * 128) / 2048, 256, 0, stream>>>(R, pbest, pidx, Eq, rbuf, qsum,
                                                           vqp + q * 1024, q == 0 ? 1 : 0,
                                                           Rsp, ids_f + q);
    }
    k_vq_acc<<<1, 256, 0, stream>>>(vqp, vl);

    // dec weight splits (rbuf dead after last vq_update)
    k_wsplit<<<(128 * 256) / 256, 256, 0, stream>>>(dec_w0, WtD0, 128, 256);
    k_wsplit<<<(256 * 512) / 256, 256, 0, stream>>>(dec_w1, WtD1, 256, 512);
    k_wsplit<<<(512 * 768) / 256, 256, 0, stream>>>(dec_w2, WtD2, 512, 768);

    k_mfma_rms<256><<<NB / 64, 512, 0, stream>>>(qsum, WtD0, dec_b0, dec_g0, h1, 128);
    k_mfma_rms<512><<<NB / 64, 512, 0, stream>>>(h1, WtD1, dec_b1, dec_g1, h0, 256);

    dim3 g2(NB / 64, 3);
    k_mfma_dec2<<<g2, 512, 0, stream>>>(h0, WtD2, dec_b2, xn, rl, 512);
}

// Round 11
// 835.217 us; speedup vs baseline: 1.5449x; 1.0277x over previous
//
#include <hip/hip_runtime.h>
#include <math.h>

#define NB 16384
#define DIN 768

typedef _Float16 f16x8 __attribute__((ext_vector_type(8)));
typedef float f32x16 __attribute__((ext_vector_type(16)));

// ---------------- small kernels ----------------

// also zeroes the recon-loss accumulator (rl)
__global__ void k_norm(const float* __restrict__ x, const float* __restrict__ m,
                       const float* __restrict__ s, float* __restrict__ xn,
                       float* __restrict__ rl) {
    int i = blockIdx.x * 256 + threadIdx.x;          // 16384*768 total
    int j = i % DIN;
    xn[i] = (x[i] - m[j]) / s[j];
    if (i == 0) *rl = 0.f;
}

// fused cbnorm + esplit (one wave per codebook row, 4 rows/block):
// reads each cb row ONCE; writes cbn[row] = ||E||^2 * 4096 AND the fp16 hi/lo
// granule layout (verbatim formula from the verified k_esplit):
//   base = q*2097152 + (c>>6)*16384 + (c&63)*8 + (k&7)
//   hi at base + (k>>3)*512 ; lo at base + (16+(k>>3))*512 ; scale 256
__global__ void k_cbesplit(const float* __restrict__ cb, float* __restrict__ cbn,
                           _Float16* __restrict__ Esp) {
    int row = blockIdx.x * 4 + (threadIdx.x >> 6);   // 4*8192 rows total
    int lane = threadIdx.x & 63;
    int q = row >> 13, c = row & 8191;
    const float* p = cb + (size_t)row * 128;
    float v0 = p[lane], v1 = p[lane + 64];
    float s = v0 * v0 + v1 * v1;
    #pragma unroll
    for (int m = 32; m >= 1; m >>= 1) s += __shfl_xor(s, m, 64);
    if (lane == 0) cbn[row] = s * 4096.f;
    size_t base0 = (size_t)q * 2097152 + (size_t)(c >> 6) * 16384 + (size_t)(c & 63) * 8;
    #pragma unroll
    for (int e = 0; e < 2; e++) {
        int k = lane + e * 64;
        float v = (e ? v1 : v0) * 256.f;
        _Float16 hi = (_Float16)v;
        _Float16 lo = (_Float16)(v - (float)hi);
        size_t base = base0 + (k & 7);
        Esp[base + (size_t)(k >> 3) * 512] = hi;
        Esp[base + (size_t)(16 + (k >> 3)) * 512] = lo;
    }
}

// ---------------- weight transpose-split, 3 layers per launch ----------------
// W (K x N fp32) -> Wt halfs, granule (kc, s, c): ((kc*8+s)*N + c)*8 + j
// k = kc*32 + t*16 + g*8 + j ; s = t*2+g (hi), 4+t*2+g (lo). Scale 256.
// Block-range dispatch: blocks [0,nb0) -> layer0, [nb0,nb0+nb1) -> layer1, rest -> layer2.
__device__ __forceinline__ void wsplit_body(const float* W, _Float16* Wt,
                                            int N, int i) {
    int k = i / N, c = i - k * N;
    float v = W[i] * 256.f;
    _Float16 hi = (_Float16)v;
    _Float16 lo = (_Float16)(v - (float)hi);
    int kc = k >> 5, kin = k & 31;
    int t = kin >> 4, gg = (kin >> 3) & 1, j = kin & 7;
    size_t base = ((size_t)(kc * 8) * N + c) * 8 + j;
    Wt[base + (size_t)(t * 2 + gg) * N * 8] = hi;
    Wt[base + (size_t)(4 + t * 2 + gg) * N * 8] = lo;
}

__global__ void k_wsplit3(const float* __restrict__ W0, _Float16* __restrict__ Wt0, int N0, int nb0,
                          const float* __restrict__ W1, _Float16* __restrict__ Wt1, int N1, int nb1,
                          const float* __restrict__ W2, _Float16* __restrict__ Wt2, int N2) {
    int b = blockIdx.x;
    if (b < nb0) {
        wsplit_body(W0, Wt0, N0, b * 256 + threadIdx.x);
    } else if (b < nb0 + nb1) {
        wsplit_body(W1, Wt1, N1, (b - nb0) * 256 + threadIdx.x);
    } else {
        wsplit_body(W2, Wt2, N2, (b - nb0 - nb1) * 256 + threadIdx.x);
    }
}

// ---------------- fused MFMA Linear + ReLU + RMSNorm ----------------
// v3: optional rsp output — epilogue also writes the fp16 hi/lo split
// (scale -32) of the result, removing the separate k_split pass (value v is
// bitwise identical to what k_split would have re-read from out[]).
template <int N>
__global__ __launch_bounds__(512, 2) void k_mfma_rms(
    const float* __restrict__ A, const _Float16* __restrict__ Wt,
    const float* __restrict__ bias, const float* __restrict__ g,
    float* __restrict__ out, int K, _Float16* __restrict__ rsp) {
    constexpr int CT = N / 128;               // col-tiles per wave
    __shared__ __align__(16) _Float16 Bs[2][N * 64];
    __shared__ float ssbuf[64][4];
    const int tid = threadIdx.x;
    const int w = tid >> 6, lane = tid & 63;
    const int wr = w >> 2, wc = w & 3;
    const int g32 = lane >> 5, cl = lane & 31;
    const int row0 = blockIdx.x * 64;
    const int NC = K >> 5;                    // chunks of 32 k (always even)

    const float* ap = A + (size_t)(row0 + wr * 32 + cl) * K + g32 * 8;

    f32x16 acc[CT];
    #pragma unroll
    for (int tt = 0; tt < CT; tt++)
        #pragma unroll
        for (int m = 0; m < 16; m++) acc[tt][m] = 0.f;

    float4 Ar0[4], Ar1[4];

    auto STAGE = [&](int ch, int b) {
        const _Float16* gp = Wt + (size_t)ch * 8 * N * 8;
        #pragma unroll
        for (int p = 0; p < N / 64; p++) {
            int f = tid + 512 * p;
            __builtin_amdgcn_global_load_lds(
                (const __attribute__((address_space(1))) void*)(gp + (size_t)f * 8),
                (__attribute__((address_space(3))) void*)(&Bs[b][(size_t)f * 8]),
                16, 0, 0);
        }
    };
    auto AISSUE = [&](int ch, float4* Ar) {
        const float* bsrc = ap + ch * 32;
        Ar[0] = *(const float4*)(bsrc);
        Ar[1] = *(const float4*)(bsrc + 4);
        Ar[2] = *(const float4*)(bsrc + 16);
        Ar[3] = *(const float4*)(bsrc + 20);
    };
    auto COMPUTE = [&](int b, const float4* Ar) {
        #pragma unroll
        for (int t = 0; t < 2; t++) {
            float vv[8] = {Ar[t * 2].x, Ar[t * 2].y, Ar[t * 2].z, Ar[t * 2].w,
                           Ar[t * 2 + 1].x, Ar[t * 2 + 1].y, Ar[t * 2 + 1].z, Ar[t * 2 + 1].w};
            f16x8 ah, al;
            #pragma unroll
            for (int j = 0; j < 8; j++) {
                float v = vv[j] * 16.f;
                _Float16 h = (_Float16)v;
                ah[j] = h;
                al[j] = (_Float16)(v - (float)h);
            }
            f16x8 bh[CT], bl[CT];
            #pragma unroll
            for (int tt = 0; tt < CT; tt++) {
                int c = wc * (N / 4) + tt * 32 + cl;
                bh[tt] = *(const f16x8*)&Bs[b][((size_t)(t * 2 + g32) * N + c) * 8];
                bl[tt] = *(const f16x8*)&Bs[b][((size_t)(4 + t * 2 + g32) * N + c) * 8];
            }
            #pragma unroll
            for (int tt = 0; tt < CT; tt++)
                acc[tt] = __builtin_amdgcn_mfma_f32_32x32x16_f16(ah, bh[tt], acc[tt], 0, 0, 0);
            #pragma unroll
            for (int tt = 0; tt < CT; tt++)
                acc[tt] = __builtin_amdgcn_mfma_f32_32x32x16_f16(al, bh[tt], acc[tt], 0, 0, 0);
            #pragma unroll
            for (int tt = 0; tt < CT; tt++)
                acc[tt] = __builtin_amdgcn_mfma_f32_32x32x16_f16(ah, bl[tt], acc[tt], 0, 0, 0);
        }
    };

    AISSUE(0, Ar0);
    STAGE(0, 0);
    for (int ch = 0; ch < NC; ch += 2) {
        __syncthreads();                      // drains stage(ch) + A loads
        STAGE(ch + 1, 1);
        AISSUE(ch + 1, Ar1);
        COMPUTE(0, Ar0);
        __syncthreads();                      // drains stage(ch+1)
        if (ch + 2 < NC) { STAGE(ch + 2, 0); AISSUE(ch + 2, Ar0); }
        COMPUTE(1, Ar1);
    }

    // epilogue: /4096 + bias + relu + rmsnorm (+ optional fp16 split out)
    constexpr float INV = 1.f / 4096.f;
    float bb[CT], gv[CT];
    #pragma unroll
    for (int tt = 0; tt < CT; tt++) {
        int c = wc * (N / 4) + tt * 32 + cl;
        bb[tt] = bias[c];
        gv[tt] = g[c];
    }
    float ssm[16];
    #pragma unroll
    for (int m = 0; m < 16; m++) ssm[m] = 0.f;
    #pragma unroll
    for (int tt = 0; tt < CT; tt++)
        #pragma unroll
        for (int m = 0; m < 16; m++) {
            float v = fmaf(acc[tt][m], INV, bb[tt]);
            v = v > 0.f ? v : 0.f;
            acc[tt][m] = v;
            ssm[m] = fmaf(v, v, ssm[m]);
        }
    #pragma unroll
    for (int mask = 1; mask < 32; mask <<= 1)
        #pragma unroll
        for (int m = 0; m < 16; m++) ssm[m] += __shfl_xor(ssm[m], mask, 64);
    if (cl == 0) {
        #pragma unroll
        for (int m = 0; m < 16; m++) {
            int rl = wr * 32 + (m & 3) + 8 * (m >> 2) + 4 * g32;
            ssbuf[rl][wc] = ssm[m];
        }
    }
    __syncthreads();
    #pragma unroll
    for (int m = 0; m < 16; m++) {
        int rl = wr * 32 + (m & 3) + 8 * (m >> 2) + 4 * g32;
        float s4 = (ssbuf[rl][0] + ssbuf[rl][1]) + (ssbuf[rl][2] + ssbuf[rl][3]);
        float sc = 1.0f / sqrtf(s4 * (1.0f / (float)N) + 1e-6f);
        #pragma unroll
        for (int tt = 0; tt < CT; tt++) {
            int c = wc * (N / 4) + tt * 32 + cl;
            float v = acc[tt][m] * sc * gv[tt];
            out[(size_t)(row0 + rl) * N + c] = v;
            if (rsp) {
                float rs = v * -32.f;
                _Float16 h = (_Float16)rs;
                rsp[(size_t)(row0 + rl) * 256 + c] = h;
                rsp[(size_t)(row0 + rl) * 256 + 128 + c] = (_Float16)(rs - (float)h);
            }
        }
    }
}

// ---------------- final MFMA Linear (512->768) + recon loss ----------------
// v2: product-major COMPUTE reorder (CT=2)
__global__ __launch_bounds__(512, 2) void k_mfma_dec2(
    const float* __restrict__ A, const _Float16* __restrict__ Wt,
    const float* __restrict__ bias, float* __restrict__ rec,
    float* __restrict__ loss_acc, int K) {
    constexpr int NT = 256, NF = 768, CT = 2;
    __shared__ __align__(16) _Float16 Bs[2][NT * 64];
    __shared__ float red[8];
    const int tid = threadIdx.x;
    const int w = tid >> 6, lane = tid & 63;
    const int wr = w >> 2, wc = w & 3;
    const int g32 = lane >> 5, cl = lane & 31;
    const int row0 = blockIdx.x * 64;
    const int col0 = blockIdx.y * NT;
    const int NC = K >> 5;

    const float* ap = A + (size_t)(row0 + wr * 32 + cl) * K + g32 * 8;

    f32x16 acc[CT];
    #pragma unroll
    for (int tt = 0; tt < CT; tt++)
        #pragma unroll
        for (int m = 0; m < 16; m++) acc[tt][m] = 0.f;

    float4 Ar0[4], Ar1[4];

    auto STAGE = [&](int ch, int b) {
        #pragma unroll
        for (int p = 0; p < 4; p++) {
            int f = tid + 512 * p;
            int s = f >> 8, cloc = f & 255;
            const _Float16* gp = Wt + ((size_t)(ch * 8 + s) * NF + col0 + cloc) * 8;
            __builtin_amdgcn_global_load_lds(
                (const __attribute__((address_space(1))) void*)gp,
                (__attribute__((address_space(3))) void*)(&Bs[b][(size_t)f * 8]),
                16, 0, 0);
        }
    };
    auto AISSUE = [&](int ch, float4* Ar) {
        const float* bsrc = ap + ch * 32;
        Ar[0] = *(const float4*)(bsrc);
        Ar[1] = *(const float4*)(bsrc + 4);
        Ar[2] = *(const float4*)(bsrc + 16);
        Ar[3] = *(const float4*)(bsrc + 20);
    };
    auto COMPUTE = [&](int b, const float4* Ar) {
        #pragma unroll
        for (int t = 0; t < 2; t++) {
            float vv[8] = {Ar[t * 2].x, Ar[t * 2].y, Ar[t * 2].z, Ar[t * 2].w,
                           Ar[t * 2 + 1].x, Ar[t * 2 + 1].y, Ar[t * 2 + 1].z, Ar[t * 2 + 1].w};
            f16x8 ah, al;
            #pragma unroll
            for (int j = 0; j < 8; j++) {
                float v = vv[j] * 16.f;
                _Float16 h = (_Float16)v;
                ah[j] = h;
                al[j] = (_Float16)(v - (float)h);
            }
            f16x8 bh[CT], bl[CT];
            #pragma unroll
            for (int tt = 0; tt < CT; tt++) {
                int c = wc * 64 + tt * 32 + cl;
                bh[tt] = *(const f16x8*)&Bs[b][((size_t)(t * 2 + g32) * NT + c) * 8];
                bl[tt] = *(const f16x8*)&Bs[b][((size_t)(4 + t * 2 + g32) * NT + c) * 8];
            }
            #pragma unroll
            for (int tt = 0; tt < CT; tt++)
                acc[tt] = __builtin_amdgcn_mfma_f32_32x32x16_f16(ah, bh[tt], acc[tt], 0, 0, 0);
            #pragma unroll
            for (int tt = 0; tt < CT; tt++)
                acc[tt] = __builtin_amdgcn_mfma_f32_32x32x16_f16(al, bh[tt], acc[tt], 0, 0, 0);
            #pragma unroll
            for (int tt = 0; tt < CT; tt++)
                acc[tt] = __builtin_amdgcn_mfma_f32_32x32x16_f16(ah, bl[tt], acc[tt], 0, 0, 0);
        }
    };

    AISSUE(0, Ar0);
    STAGE(0, 0);
    for (int ch = 0; ch < NC; ch += 2) {
        __syncthreads();
        STAGE(ch + 1, 1);
        AISSUE(ch + 1, Ar1);
        COMPUTE(0, Ar0);
        __syncthreads();
        if (ch + 2 < NC) { STAGE(ch + 2, 0); AISSUE(ch + 2, Ar0); }
        COMPUTE(1, Ar1);
    }

    constexpr float INV = 1.f / 4096.f;
    float lsum = 0.f;
    #pragma unroll
    for (int tt = 0; tt < CT; tt++) {
        int cg = col0 + wc * 64 + tt * 32 + cl;
        float bb = bias[cg];
        #pragma unroll
        for (int m = 0; m < 16; m++) {
            int rl = wr * 32 + (m & 3) + 8 * (m >> 2) + 4 * g32;
            float v = fmaf(acc[tt][m], INV, bb);
            size_t o = (size_t)(row0 + rl) * NF + cg;
            float e = v - rec[o];             // rec holds xn here
            lsum = fmaf(e, e, lsum);
            rec[o] = v;
        }
    }
    #pragma unroll
    for (int mask = 1; mask < 64; mask <<= 1) lsum += __shfl_xor(lsum, mask, 64);
    if (lane == 0) red[w] = lsum;
    __syncthreads();
    if (tid == 0) {
        float t = 0.f;
        #pragma unroll
        for (int i = 0; i < 8; i++) t += red[i];
        atomicAdd(loss_acc, t * (1.0f / ((float)NB * (float)DIN)));
    }
}

// ---------------- VQ: fp16 hi/lo split MFMA scores + partial argmin (v6) -----
// (verified round 8/10: LDS double-buffered 64-code chunks, 4 chains, d=3)
__global__ __launch_bounds__(256, 2) void k_vq_argmin_mfma(
    const _Float16* __restrict__ Rsp, const _Float16* __restrict__ Esp,
    const float* __restrict__ cbnS,
    float* __restrict__ pbest, int* __restrict__ pidx) {
    __shared__ __align__(16) _Float16 Es[2][16384];   // 2 x 32KB (64 codes each)
    const int tid = threadIdx.x;
    const int w = tid >> 6, lane = tid & 63;
    const int g = lane >> 5, cl31 = lane & 31;
    const int rt0 = blockIdx.x * 256 + w * 64;        // wave's 64 rows
    const int cbase = blockIdx.y * 512;
    const int ch0 = blockIdx.y * 8;

    f16x8 Rh0[8], Rl0[8], Rh1[8], Rl1[8];
    {
        const _Float16* rp0 = Rsp + (size_t)(rt0 + cl31) * 256 + g * 8;
        const _Float16* rp1 = rp0 + 32 * 256;
        #pragma unroll
        for (int kc = 0; kc < 8; kc++) {
            Rh0[kc] = *(const f16x8*)(rp0 + kc * 16);
            Rl0[kc] = *(const f16x8*)(rp0 + 128 + kc * 16);
            Rh1[kc] = *(const f16x8*)(rp1 + kc * 16);
            Rl1[kc] = *(const f16x8*)(rp1 + 128 + kc * 16);
        }
    }

    float best0 = 3.402823466e+38f, best1 = 3.402823466e+38f;
    int bidx0 = 0, bidx1 = 0;

    auto STAGE = [&](int gch, int b) {
        const _Float16* gp = Esp + (size_t)gch * 16384;
        #pragma unroll
        for (int p = 0; p < 8; p++) {
            int f = tid + 256 * p;
            __builtin_amdgcn_global_load_lds(
                (const __attribute__((address_space(1))) void*)(gp + (size_t)f * 8),
                (__attribute__((address_space(3))) void*)(&Es[b][(size_t)f * 8]),
                16, 0, 0);
        }
    };

    STAGE(ch0, 0);
    for (int ch = 0; ch < 8; ch++) {
        const int buf = ch & 1;
        const int c0c = cbase + ch * 64;
        // cbn for both 32-code subtiles, loaded BEFORE the barrier
        float cnv0[16], cnv1[16];
        #pragma unroll
        for (int q = 0; q < 4; q++) {
            float4 v0 = *(const float4*)(cbnS + c0c + q * 8 + 4 * g);
            float4 v1 = *(const float4*)(cbnS + c0c + 32 + q * 8 + 4 * g);
            cnv0[q * 4 + 0] = v0.x; cnv0[q * 4 + 1] = v0.y;
            cnv0[q * 4 + 2] = v0.z; cnv0[q * 4 + 3] = v0.w;
            cnv1[q * 4 + 0] = v1.x; cnv1[q * 4 + 1] = v1.y;
            cnv1[q * 4 + 2] = v1.z; cnv1[q * 4 + 3] = v1.w;
        }
        __syncthreads();                      // stage(ch) landed; buf readable
        if (ch < 7) STAGE(ch0 + ch + 1, buf ^ 1);
        #pragma unroll
        for (int st = 0; st < 2; st++) {
            const int cloc = st * 32 + cl31;
            const float* cnv = st ? cnv1 : cnv0;
            f32x16 c00, c01, c10, c11;
            #pragma unroll
            for (int m = 0; m < 16; m++) { c00[m] = 0.f; c01[m] = 0.f; c10[m] = 0.f; c11[m] = 0.f; }
            __builtin_amdgcn_s_setprio(1);
            #pragma unroll
            for (int kc = 0; kc < 8; kc++) {
                int sh = kc * 2 + g;
                f16x8 eh = *(const f16x8*)&Es[buf][sh * 512 + cloc * 8];
                f16x8 el = *(const f16x8*)&Es[buf][(16 + sh) * 512 + cloc * 8];
                c00 = __builtin_amdgcn_mfma_f32_32x32x16_f16(eh, Rh0[kc], c00, 0, 0, 0);
                c01 = __builtin_amdgcn_mfma_f32_32x32x16_f16(eh, Rh1[kc], c01, 0, 0, 0);
                c10 = __builtin_amdgcn_mfma_f32_32x32x16_f16(eh, Rl0[kc], c10, 0, 0, 0);
                c00 = __builtin_amdgcn_mfma_f32_32x32x16_f16(el, Rh0[kc], c00, 0, 0, 0);
                c01 = __builtin_amdgcn_mfma_f32_32x32x16_f16(el, Rh1[kc], c01, 0, 0, 0);
                c11 = __builtin_amdgcn_mfma_f32_32x32x16_f16(eh, Rl1[kc], c11, 0, 0, 0);
            }
            __builtin_amdgcn_s_setprio(0);
            // running argmin (D-row m -> code c0c + st*32 + 4g + (m&3)+8*(m>>2))
            const int c0g = c0c + st * 32 + 4 * g;
            #pragma unroll
            for (int m = 0; m < 16; m++) {
                int c = c0g + ((m & 3) + 8 * (m >> 2));
                float s0 = (c00[m] + c10[m]) + cnv[m];
                float s1 = (c01[m] + c11[m]) + cnv[m];
                if (s0 < best0) { best0 = s0; bidx0 = c; }
                if (s1 < best1) { best1 = s1; bidx1 = c; }
            }
        }
    }

    // merge lane-halves (same row, complementary code sets); tie -> smaller idx
    {
        float ob = __shfl_xor(best0, 32, 64);
        int oi = __shfl_xor(bidx0, 32, 64);
        if (ob < best0 || (ob == best0 && oi < bidx0)) { best0 = ob; bidx0 = oi; }
        ob = __shfl_xor(best1, 32, 64);
        oi = __shfl_xor(bidx1, 32, 64);
        if (ob < best1 || (ob == best1 && oi < bidx1)) { best1 = ob; bidx1 = oi; }
    }
    if (lane < 32) {
        const int part = blockIdx.y;
        pbest[(size_t)part * NB + rt0 + cl31] = best0;
        pidx [(size_t)part * NB + rt0 + cl31] = bidx0;
        pbest[(size_t)part * NB + rt0 + 32 + cl31] = best1;
        pidx [(size_t)part * NB + rt0 + 32 + cl31] = bidx1;
    }
}

// fused strip-merge + gather + residual update + qsum + vq_loss partial (v4):
// 16-strip merge via 4-step shfl_xor (strip = lane&15; exact, associative
// tie-break). lastq skips the dead Rout/Rsp writes of the final quantizer.
__global__ void k_vq_update(const float* __restrict__ Rin,
                            const float* __restrict__ pbest, const int* __restrict__ pidx,
                            const float* __restrict__ E, float* __restrict__ Rout,
                            float* __restrict__ qsum, float* __restrict__ part,
                            int firstq, int lastq, _Float16* __restrict__ Rsp,
                            float* __restrict__ ids_f) {
    __shared__ float ps[4];
    int t = blockIdx.x * 256 + threadIdx.x;   // NB*128/8 threads
    int i0 = t * 8;
    int row = i0 >> 7, d0 = i0 & 127;
    int lane = threadIdx.x & 63;
    // strip-merge: this thread owns strip s = lane&15 of its row
    float b = pbest[(size_t)(lane & 15) * NB + row];
    int bi = pidx[(size_t)(lane & 15) * NB + row];
    #pragma unroll
    for (int m = 1; m < 16; m <<= 1) {
        float ob = __shfl_xor(b, m, 64);
        int oi = __shfl_xor(bi, m, 64);
        if (ob < b || (ob == b && oi < bi)) { b = ob; bi = oi; }
    }
    if (d0 == 0) ids_f[(size_t)row * 4] = (float)bi;
    const float* ep = E + (size_t)bi * 128 + d0;
    float4 e0 = *(const float4*)ep, e1 = *(const float4*)(ep + 4);
    float4 r0 = *(const float4*)&Rin[i0], r1 = *(const float4*)&Rin[i0 + 4];
    float rv[8] = {r0.x - e0.x, r0.y - e0.y, r0.z - e0.z, r0.w - e0.w,
                   r1.x - e1.x, r1.y - e1.y, r1.z - e1.z, r1.w - e1.w};
    if (!lastq) {
        *(float4*)&Rout[i0]     = make_float4(rv[0], rv[1], rv[2], rv[3]);
        *(float4*)&Rout[i0 + 4] = make_float4(rv[4], rv[5], rv[6], rv[7]);
    }
    if (firstq) {
        *(float4*)&qsum[i0] = e0;
        *(float4*)&qsum[i0 + 4] = e1;
    } else {
        float4 q0 = *(const float4*)&qsum[i0], q1 = *(const float4*)&qsum[i0 + 4];
        *(float4*)&qsum[i0]     = make_float4(q0.x + e0.x, q0.y + e0.y, q0.z + e0.z, q0.w + e0.w);
        *(float4*)&qsum[i0 + 4] = make_float4(q1.x + e1.x, q1.y + e1.y, q1.z + e1.z, q1.w + e1.w);
    }
    float p = 0.f;
    if (!lastq) {
        f16x8 hi, lo;
        #pragma unroll
        for (int j = 0; j < 8; j++) {
            float rs = rv[j] * -32.f;
            _Float16 h = (_Float16)rs;
            hi[j] = h;
            lo[j] = (_Float16)(rs - (float)h);
            p = fmaf(rv[j], rv[j], p);
        }
        *(f16x8*)&Rsp[(size_t)row * 256 + d0] = hi;
        *(f16x8*)&Rsp[(size_t)row * 256 + 128 + d0] = lo;
    } else {
        #pragma unroll
        for (int j = 0; j < 8; j++) p = fmaf(rv[j], rv[j], p);
    }
    #pragma unroll
    for (int m = 1; m < 64; m <<= 1) p += __shfl_xor(p, m, 64);
    int wv = threadIdx.x >> 6;
    if (lane == 0) ps[wv] = p;
    __syncthreads();
    if (threadIdx.x == 0)
        part[blockIdx.x] = (ps[0] + ps[1]) + (ps[2] + ps[3]);
}

// sum the 4*1024 per-block partials into the vq_loss scalar (single writer)
__global__ void k_vq_acc(const float* __restrict__ part, float* __restrict__ vl) {
    __shared__ float ps[4];
    float s = 0.f;
    for (int i = threadIdx.x; i < 4096; i += 256) s += part[i];
    #pragma unroll
    for (int m = 1; m < 64; m <<= 1) s += __shfl_xor(s, m, 64);
    int lane = threadIdx.x & 63, wv = threadIdx.x >> 6;
    if (lane == 0) ps[wv] = s;
    __syncthreads();
    if (threadIdx.x == 0)
        *vl = ((ps[0] + ps[1]) + (ps[2] + ps[3])) * (1.25f / ((float)NB * 128.f));
}

// ---------------- launch ----------------

extern "C" void kernel_launch(void* const* d_in, const int* in_sizes, int n_in,
                              void* d_out, int out_size, void* d_ws, size_t ws_size,
                              hipStream_t stream) {
    (void)in_sizes; (void)n_in; (void)out_size; (void)ws_size;
    const float* x        = (const float*)d_in[0];
    const float* emb_mean = (const float*)d_in[1];
    const float* emb_std  = (const float*)d_in[2];
    const float* enc_w0 = (const float*)d_in[3];
    const float* enc_b0 = (const float*)d_in[4];
    const float* enc_g0 = (const float*)d_in[5];
    const float* enc_w1 = (const float*)d_in[6];
    const float* enc_b1 = (const float*)d_in[7];
    const float* enc_g1 = (const float*)d_in[8];
    const float* enc_w2 = (const float*)d_in[9];
    const float* enc_b2 = (const float*)d_in[10];
    const float* enc_g2 = (const float*)d_in[11];
    const float* cb     = (const float*)d_in[12];
    const float* dec_w0 = (const float*)d_in[13];
    const float* dec_b0 = (const float*)d_in[14];
    const float* dec_g0 = (const float*)d_in[15];
    const float* dec_w1 = (const float*)d_in[16];
    const float* dec_b1 = (const float*)d_in[17];
    const float* dec_g1 = (const float*)d_in[18];
    const float* dec_w2 = (const float*)d_in[19];
    const float* dec_b2 = (const float*)d_in[20];

    float* out   = (float*)d_out;
    float* xn    = out;                        // recon region doubles as xn scratch
    float* ids_f = out + (size_t)NB * DIN;
    float* rl    = out + (size_t)NB * DIN + (size_t)NB * 4;
    float* vl    = rl + 1;

    float* ws   = (float*)d_ws;
    float* h0   = ws;                           // 16384*512
    float* h1   = h0 + (size_t)NB * 512;        // 16384*256
    float* h2   = h1 + (size_t)NB * 256;        // 16384*128
    float* rbuf = h2 + (size_t)NB * 128;        // 16384*128
    float* qsum = rbuf + (size_t)NB * 128;      // 16384*128
    float* cbn  = qsum + (size_t)NB * 128;      // 4*8192
    int*   idxb = (int*)(cbn + 4 * 8192);       // 16384 (unused, layout keep)
    float* vqp  = (float*)(idxb + NB);          // 4*1024 loss partials

    // VQ scratch in h0 (free between enc1-read and dec1-write):
    float*    pbest = h0;                                   // 16*16384
    int*      pidx  = (int*)(h0 + 16 * (size_t)NB);         // 16*16384
    _Float16* Rsp   = (_Float16*)(h0 + 32 * (size_t)NB);
    _Float16* Esp   = (_Float16*)(h0 + 32 * (size_t)NB + (size_t)NB * 128);

    // weight splits live in rbuf: enc set dead before VQ writes rbuf (q=0
    // update); dec set written after the last vq_update reads rbuf.
    _Float16* WtE0 = (_Float16*)rbuf;           // 768*512*2 = 786432 halfs
    _Float16* WtE1 = WtE0 + 786432;             // 512*256*2 = 262144
    _Float16* WtE2 = WtE0 + 1048576;            // 256*128*2 =  65536
    _Float16* WtD0 = (_Float16*)rbuf;           // 128*256*2 =  65536
    _Float16* WtD1 = WtD0 + 65536;              // 256*512*2 = 262144
    _Float16* WtD2 = WtD0 + 327680;             // 512*768*2 = 786432

    k_norm<<<(NB * DIN) / 256, 256, 0, stream>>>(x, emb_mean, emb_std, xn, rl);

    // enc weight splits: one launch, block-range dispatch (1536+512+128 blocks)
    k_wsplit3<<<2176, 256, 0, stream>>>(enc_w0, WtE0, 512, 1536,
                                        enc_w1, WtE1, 256, 512,
                                        enc_w2, WtE2, 128);

    k_mfma_rms<512><<<NB / 64, 512, 0, stream>>>(xn, WtE0, enc_b0, enc_g0, h0, 768, nullptr);
    k_mfma_rms<256><<<NB / 64, 512, 0, stream>>>(h0, WtE1, enc_b1, enc_g1, h1, 512, nullptr);
    // enc2 also emits the fp16 hi/lo split (scale -32) -> k_split removed
    k_mfma_rms<128><<<NB / 64, 512, 0, stream>>>(h1, WtE2, enc_b2, enc_g2, h2, 256, Rsp);

    // fused cbnorm + esplit (into h0 region, after enc1 consumed h0)
    k_cbesplit<<<(4 * 8192) / 4, 256, 0, stream>>>(cb, cbn, Esp);

    for (int q = 0; q < 4; q++) {
        const float* R = (q == 0) ? h2 : rbuf;
        const float* Eq = cb + (size_t)q * 8192 * 128;
        const _Float16* EspQ = Esp + (size_t)q * 2097152;
        dim3 gq(NB / 256, 16);
        k_vq_argmin_mfma<<<gq, 256, 0, stream>>>(Rsp, EspQ, cbn + q * 8192, pbest, pidx);
        k_vq_update<<<(NB * 128) / 2048, 256, 0, stream>>>(R, pbest, pidx, Eq, rbuf, qsum,
                                                           vqp + q * 1024, q == 0 ? 1 : 0,
                                                           q == 3 ? 1 : 0, Rsp, ids_f + q);
    }
    k_vq_acc<<<1, 256, 0, stream>>>(vqp, vl);

    // dec weight splits: one launch (rbuf dead after last vq_update)
    k_wsplit3<<<2176, 256, 0, stream>>>(dec_w0, WtD0, 256, 128,
                                        dec_w1, WtD1, 512, 512,
                                        dec_w2, WtD2, 768);

    k_mfma_rms<256><<<NB / 64, 512, 0, stream>>>(qsum, WtD0, dec_b0, dec_g0, h1, 128, nullptr);
    k_mfma_rms<512><<<NB / 64, 512, 0, stream>>>(h1, WtD1, dec_b1, dec_g1, h0, 256, nullptr);

    dim3 g2(NB / 64, 3);
    k_mfma_dec2<<<g2, 512, 0, stream>>>(h0, WtD2, dec_b2, xn, rl, 512);
}

// Round 12
// 820.960 us; speedup vs baseline: 1.5717x; 1.0174x over previous
//
#include <hip/hip_runtime.h>
#include <math.h>

#define NB 16384
#define DIN 768

typedef _Float16 f16x8 __attribute__((ext_vector_type(8)));
typedef float f32x16 __attribute__((ext_vector_type(16)));

// ---------------- input transforms ----------------

// fused cbnorm + esplit (one wave per codebook row, 4 rows/block):
// reads each cb row ONCE; writes cbn[row] = ||E||^2 * 4096 AND the fp16 hi/lo
// granule layout (verbatim formula from the verified k_esplit):
//   base = q*2097152 + (c>>6)*16384 + (c&63)*8 + (k&7)
//   hi at base + (k>>3)*512 ; lo at base + (16+(k>>3))*512 ; scale 256
__global__ void k_cbesplit(const float* __restrict__ cb, float* __restrict__ cbn,
                           _Float16* __restrict__ Esp) {
    int row = blockIdx.x * 4 + (threadIdx.x >> 6);   // 4*8192 rows total
    int lane = threadIdx.x & 63;
    int q = row >> 13, c = row & 8191;
    const float* p = cb + (size_t)row * 128;
    float v0 = p[lane], v1 = p[lane + 64];
    float s = v0 * v0 + v1 * v1;
    #pragma unroll
    for (int m = 32; m >= 1; m >>= 1) s += __shfl_xor(s, m, 64);
    if (lane == 0) cbn[row] = s * 4096.f;
    size_t base0 = (size_t)q * 2097152 + (size_t)(c >> 6) * 16384 + (size_t)(c & 63) * 8;
    #pragma unroll
    for (int e = 0; e < 2; e++) {
        int k = lane + e * 64;
        float v = (e ? v1 : v0) * 256.f;
        _Float16 hi = (_Float16)v;
        _Float16 lo = (_Float16)(v - (float)hi);
        size_t base = base0 + (k & 7);
        Esp[base + (size_t)(k >> 3) * 512] = hi;
        Esp[base + (size_t)(16 + (k >> 3)) * 512] = lo;
    }
}

// weight transpose-split body:
// W (K x N fp32) -> Wt halfs, granule (kc, s, c): ((kc*8+s)*N + c)*8 + j
// k = kc*32 + t*16 + g*8 + j ; s = t*2+g (hi), 4+t*2+g (lo). Scale 256.
__device__ __forceinline__ void wsplit_body(const float* W, _Float16* Wt,
                                            int N, int i) {
    int k = i / N, c = i - k * N;
    float v = W[i] * 256.f;
    _Float16 hi = (_Float16)v;
    _Float16 lo = (_Float16)(v - (float)hi);
    int kc = k >> 5, kin = k & 31;
    int t = kin >> 4, gg = (kin >> 3) & 1, j = kin & 7;
    size_t base = ((size_t)(kc * 8) * N + c) * 8 + j;
    Wt[base + (size_t)(t * 2 + gg) * N * 8] = hi;
    Wt[base + (size_t)(4 + t * 2 + gg) * N * 8] = lo;
}

// merged input-norm + enc weight splits (block-range dispatch):
// blocks [0,49152): xn = (x-m)/s (+ rl zero); then 1536/512/128 wsplit blocks.
__global__ void k_norm_wsplit(const float* __restrict__ x, const float* __restrict__ m,
                              const float* __restrict__ s, float* __restrict__ xn,
                              float* __restrict__ rl,
                              const float* __restrict__ W0, _Float16* __restrict__ Wt0,
                              const float* __restrict__ W1, _Float16* __restrict__ Wt1,
                              const float* __restrict__ W2, _Float16* __restrict__ Wt2) {
    int b = blockIdx.x;
    if (b < 49152) {
        int i = b * 256 + threadIdx.x;               // 16384*768 total
        int j = i % DIN;
        xn[i] = (x[i] - m[j]) / s[j];
        if (i == 0) *rl = 0.f;
    } else if (b < 49152 + 1536) {
        wsplit_body(W0, Wt0, 512, (b - 49152) * 256 + threadIdx.x);
    } else if (b < 49152 + 1536 + 512) {
        wsplit_body(W1, Wt1, 256, (b - 49152 - 1536) * 256 + threadIdx.x);
    } else {
        wsplit_body(W2, Wt2, 128, (b - 49152 - 2048) * 256 + threadIdx.x);
    }
}

// merged dec weight splits + vq_loss accumulation (block 2176 = acc):
__global__ void k_wsplit_acc(const float* __restrict__ W0, _Float16* __restrict__ Wt0,
                             const float* __restrict__ W1, _Float16* __restrict__ Wt1,
                             const float* __restrict__ W2, _Float16* __restrict__ Wt2,
                             const float* __restrict__ part, float* __restrict__ vl) {
    int b = blockIdx.x;
    if (b < 128) {
        wsplit_body(W0, Wt0, 256, b * 256 + threadIdx.x);
    } else if (b < 640) {
        wsplit_body(W1, Wt1, 512, (b - 128) * 256 + threadIdx.x);
    } else if (b < 2176) {
        wsplit_body(W2, Wt2, 768, (b - 640) * 256 + threadIdx.x);
    } else {
        __shared__ float ps[4];
        float s = 0.f;
        for (int i = threadIdx.x; i < 4096; i += 256) s += part[i];
        #pragma unroll
        for (int m = 1; m < 64; m <<= 1) s += __shfl_xor(s, m, 64);
        int lane = threadIdx.x & 63, wv = threadIdx.x >> 6;
        if (lane == 0) ps[wv] = s;
        __syncthreads();
        if (threadIdx.x == 0)
            *vl = ((ps[0] + ps[1]) + (ps[2] + ps[3])) * (1.25f / ((float)NB * 128.f));
    }
}

// ---------------- fused MFMA Linear + ReLU + RMSNorm ----------------
// v3: optional rsp output — epilogue also writes the fp16 hi/lo split
// (scale -32) of the result (removes the separate k_split pass).
template <int N>
__global__ __launch_bounds__(512, 2) void k_mfma_rms(
    const float* __restrict__ A, const _Float16* __restrict__ Wt,
    const float* __restrict__ bias, const float* __restrict__ g,
    float* __restrict__ out, int K, _Float16* __restrict__ rsp) {
    constexpr int CT = N / 128;               // col-tiles per wave
    __shared__ __align__(16) _Float16 Bs[2][N * 64];
    __shared__ float ssbuf[64][4];
    const int tid = threadIdx.x;
    const int w = tid >> 6, lane = tid & 63;
    const int wr = w >> 2, wc = w & 3;
    const int g32 = lane >> 5, cl = lane & 31;
    const int row0 = blockIdx.x * 64;
    const int NC = K >> 5;                    // chunks of 32 k (always even)

    const float* ap = A + (size_t)(row0 + wr * 32 + cl) * K + g32 * 8;

    f32x16 acc[CT];
    #pragma unroll
    for (int tt = 0; tt < CT; tt++)
        #pragma unroll
        for (int m = 0; m < 16; m++) acc[tt][m] = 0.f;

    float4 Ar0[4], Ar1[4];

    auto STAGE = [&](int ch, int b) {
        const _Float16* gp = Wt + (size_t)ch * 8 * N * 8;
        #pragma unroll
        for (int p = 0; p < N / 64; p++) {
            int f = tid + 512 * p;
            __builtin_amdgcn_global_load_lds(
                (const __attribute__((address_space(1))) void*)(gp + (size_t)f * 8),
                (__attribute__((address_space(3))) void*)(&Bs[b][(size_t)f * 8]),
                16, 0, 0);
        }
    };
    auto AISSUE = [&](int ch, float4* Ar) {
        const float* bsrc = ap + ch * 32;
        Ar[0] = *(const float4*)(bsrc);
        Ar[1] = *(const float4*)(bsrc + 4);
        Ar[2] = *(const float4*)(bsrc + 16);
        Ar[3] = *(const float4*)(bsrc + 20);
    };
    auto COMPUTE = [&](int b, const float4* Ar) {
        #pragma unroll
        for (int t = 0; t < 2; t++) {
            float vv[8] = {Ar[t * 2].x, Ar[t * 2].y, Ar[t * 2].z, Ar[t * 2].w,
                           Ar[t * 2 + 1].x, Ar[t * 2 + 1].y, Ar[t * 2 + 1].z, Ar[t * 2 + 1].w};
            f16x8 ah, al;
            #pragma unroll
            for (int j = 0; j < 8; j++) {
                float v = vv[j] * 16.f;
                _Float16 h = (_Float16)v;
                ah[j] = h;
                al[j] = (_Float16)(v - (float)h);
            }
            f16x8 bh[CT], bl[CT];
            #pragma unroll
            for (int tt = 0; tt < CT; tt++) {
                int c = wc * (N / 4) + tt * 32 + cl;
                bh[tt] = *(const f16x8*)&Bs[b][((size_t)(t * 2 + g32) * N + c) * 8];
                bl[tt] = *(const f16x8*)&Bs[b][((size_t)(4 + t * 2 + g32) * N + c) * 8];
            }
            #pragma unroll
            for (int tt = 0; tt < CT; tt++)
                acc[tt] = __builtin_amdgcn_mfma_f32_32x32x16_f16(ah, bh[tt], acc[tt], 0, 0, 0);
            #pragma unroll
            for (int tt = 0; tt < CT; tt++)
                acc[tt] = __builtin_amdgcn_mfma_f32_32x32x16_f16(al, bh[tt], acc[tt], 0, 0, 0);
            #pragma unroll
            for (int tt = 0; tt < CT; tt++)
                acc[tt] = __builtin_amdgcn_mfma_f32_32x32x16_f16(ah, bl[tt], acc[tt], 0, 0, 0);
        }
    };

    AISSUE(0, Ar0);
    STAGE(0, 0);
    for (int ch = 0; ch < NC; ch += 2) {
        __syncthreads();                      // drains stage(ch) + A loads
        STAGE(ch + 1, 1);
        AISSUE(ch + 1, Ar1);
        COMPUTE(0, Ar0);
        __syncthreads();                      // drains stage(ch+1)
        if (ch + 2 < NC) { STAGE(ch + 2, 0); AISSUE(ch + 2, Ar0); }
        COMPUTE(1, Ar1);
    }

    // epilogue: /4096 + bias + relu + rmsnorm (+ optional fp16 split out)
    constexpr float INV = 1.f / 4096.f;
    float bb[CT], gv[CT];
    #pragma unroll
    for (int tt = 0; tt < CT; tt++) {
        int c = wc * (N / 4) + tt * 32 + cl;
        bb[tt] = bias[c];
        gv[tt] = g[c];
    }
    float ssm[16];
    #pragma unroll
    for (int m = 0; m < 16; m++) ssm[m] = 0.f;
    #pragma unroll
    for (int tt = 0; tt < CT; tt++)
        #pragma unroll
        for (int m = 0; m < 16; m++) {
            float v = fmaf(acc[tt][m], INV, bb[tt]);
            v = v > 0.f ? v : 0.f;
            acc[tt][m] = v;
            ssm[m] = fmaf(v, v, ssm[m]);
        }
    #pragma unroll
    for (int mask = 1; mask < 32; mask <<= 1)
        #pragma unroll
        for (int m = 0; m < 16; m++) ssm[m] += __shfl_xor(ssm[m], mask, 64);
    if (cl == 0) {
        #pragma unroll
        for (int m = 0; m < 16; m++) {
            int rl = wr * 32 + (m & 3) + 8 * (m >> 2) + 4 * g32;
            ssbuf[rl][wc] = ssm[m];
        }
    }
    __syncthreads();
    #pragma unroll
    for (int m = 0; m < 16; m++) {
        int rl = wr * 32 + (m & 3) + 8 * (m >> 2) + 4 * g32;
        float s4 = (ssbuf[rl][0] + ssbuf[rl][1]) + (ssbuf[rl][2] + ssbuf[rl][3]);
        float sc = 1.0f / sqrtf(s4 * (1.0f / (float)N) + 1e-6f);
        #pragma unroll
        for (int tt = 0; tt < CT; tt++) {
            int c = wc * (N / 4) + tt * 32 + cl;
            float v = acc[tt][m] * sc * gv[tt];
            out[(size_t)(row0 + rl) * N + c] = v;
            if (rsp) {
                float rs = v * -32.f;
                _Float16 h = (_Float16)rs;
                rsp[(size_t)(row0 + rl) * 256 + c] = h;
                rsp[(size_t)(row0 + rl) * 256 + 128 + c] = (_Float16)(rs - (float)h);
            }
        }
    }
}

// ---------------- final MFMA Linear (512->768) + recon loss ----------------
// v2: product-major COMPUTE reorder (CT=2)
__global__ __launch_bounds__(512, 2) void k_mfma_dec2(
    const float* __restrict__ A, const _Float16* __restrict__ Wt,
    const float* __restrict__ bias, float* __restrict__ rec,
    float* __restrict__ loss_acc, int K) {
    constexpr int NT = 256, NF = 768, CT = 2;
    __shared__ __align__(16) _Float16 Bs[2][NT * 64];
    __shared__ float red[8];
    const int tid = threadIdx.x;
    const int w = tid >> 6, lane = tid & 63;
    const int wr = w >> 2, wc = w & 3;
    const int g32 = lane >> 5, cl = lane & 31;
    const int row0 = blockIdx.x * 64;
    const int col0 = blockIdx.y * NT;
    const int NC = K >> 5;

    const float* ap = A + (size_t)(row0 + wr * 32 + cl) * K + g32 * 8;

    f32x16 acc[CT];
    #pragma unroll
    for (int tt = 0; tt < CT; tt++)
        #pragma unroll
        for (int m = 0; m < 16; m++) acc[tt][m] = 0.f;

    float4 Ar0[4], Ar1[4];

    auto STAGE = [&](int ch, int b) {
        #pragma unroll
        for (int p = 0; p < 4; p++) {
            int f = tid + 512 * p;
            int s = f >> 8, cloc = f & 255;
            const _Float16* gp = Wt + ((size_t)(ch * 8 + s) * NF + col0 + cloc) * 8;
            __builtin_amdgcn_global_load_lds(
                (const __attribute__((address_space(1))) void*)gp,
                (__attribute__((address_space(3))) void*)(&Bs[b][(size_t)f * 8]),
                16, 0, 0);
        }
    };
    auto AISSUE = [&](int ch, float4* Ar) {
        const float* bsrc = ap + ch * 32;
        Ar[0] = *(const float4*)(bsrc);
        Ar[1] = *(const float4*)(bsrc + 4);
        Ar[2] = *(const float4*)(bsrc + 16);
        Ar[3] = *(const float4*)(bsrc + 20);
    };
    auto COMPUTE = [&](int b, const float4* Ar) {
        #pragma unroll
        for (int t = 0; t < 2; t++) {
            float vv[8] = {Ar[t * 2].x, Ar[t * 2].y, Ar[t * 2].z, Ar[t * 2].w,
                           Ar[t * 2 + 1].x, Ar[t * 2 + 1].y, Ar[t * 2 + 1].z, Ar[t * 2 + 1].w};
            f16x8 ah, al;
            #pragma unroll
            for (int j = 0; j < 8; j++) {
                float v = vv[j] * 16.f;
                _Float16 h = (_Float16)v;
                ah[j] = h;
                al[j] = (_Float16)(v - (float)h);
            }
            f16x8 bh[CT], bl[CT];
            #pragma unroll
            for (int tt = 0; tt < CT; tt++) {
                int c = wc * 64 + tt * 32 + cl;
                bh[tt] = *(const f16x8*)&Bs[b][((size_t)(t * 2 + g32) * NT + c) * 8];
                bl[tt] = *(const f16x8*)&Bs[b][((size_t)(4 + t * 2 + g32) * NT + c) * 8];
            }
            #pragma unroll
            for (int tt = 0; tt < CT; tt++)
                acc[tt] = __builtin_amdgcn_mfma_f32_32x32x16_f16(ah, bh[tt], acc[tt], 0, 0, 0);
            #pragma unroll
            for (int tt = 0; tt < CT; tt++)
                acc[tt] = __builtin_amdgcn_mfma_f32_32x32x16_f16(al, bh[tt], acc[tt], 0, 0, 0);
            #pragma unroll
            for (int tt = 0; tt < CT; tt++)
                acc[tt] = __builtin_amdgcn_mfma_f32_32x32x16_f16(ah, bl[tt], acc[tt], 0, 0, 0);
        }
    };

    AISSUE(0, Ar0);
    STAGE(0, 0);
    for (int ch = 0; ch < NC; ch += 2) {
        __syncthreads();
        STAGE(ch + 1, 1);
        AISSUE(ch + 1, Ar1);
        COMPUTE(0, Ar0);
        __syncthreads();
        if (ch + 2 < NC) { STAGE(ch + 2, 0); AISSUE(ch + 2, Ar0); }
        COMPUTE(1, Ar1);
    }

    constexpr float INV = 1.f / 4096.f;
    float lsum = 0.f;
    #pragma unroll
    for (int tt = 0; tt < CT; tt++) {
        int cg = col0 + wc * 64 + tt * 32 + cl;
        float bb = bias[cg];
        #pragma unroll
        for (int m = 0; m < 16; m++) {
            int rl = wr * 32 + (m & 3) + 8 * (m >> 2) + 4 * g32;
            float v = fmaf(acc[tt][m], INV, bb);
            size_t o = (size_t)(row0 + rl) * NF + cg;
            float e = v - rec[o];             // rec holds xn here
            lsum = fmaf(e, e, lsum);
            rec[o] = v;
        }
    }
    #pragma unroll
    for (int mask = 1; mask < 64; mask <<= 1) lsum += __shfl_xor(lsum, mask, 64);
    if (lane == 0) red[w] = lsum;
    __syncthreads();
    if (tid == 0) {
        float t = 0.f;
        #pragma unroll
        for (int i = 0; i < 8; i++) t += red[i];
        atomicAdd(loss_acc, t * (1.0f / ((float)NB * (float)DIN)));
    }
}

// ---------------- VQ: fp16 hi/lo split MFMA scores + partial argmin (v6.1) ---
// v6 inner loop verbatim; STRIPS 16 -> 8 (grid y=8, 16 chunks/block):
// 512 blocks = exactly 2 blocks/CU, single dispatch pass, no tail; R-fragment
// prologue amortized over 2x chunks.
__global__ __launch_bounds__(256, 2) void k_vq_argmin_mfma(
    const _Float16* __restrict__ Rsp, const _Float16* __restrict__ Esp,
    const float* __restrict__ cbnS,
    float* __restrict__ pbest, int* __restrict__ pidx) {
    __shared__ __align__(16) _Float16 Es[2][16384];   // 2 x 32KB (64 codes each)
    const int tid = threadIdx.x;
    const int w = tid >> 6, lane = tid & 63;
    const int g = lane >> 5, cl31 = lane & 31;
    const int rt0 = blockIdx.x * 256 + w * 64;        // wave's 64 rows
    const int cbase = blockIdx.y * 1024;
    const int ch0 = blockIdx.y * 16;

    f16x8 Rh0[8], Rl0[8], Rh1[8], Rl1[8];
    {
        const _Float16* rp0 = Rsp + (size_t)(rt0 + cl31) * 256 + g * 8;
        const _Float16* rp1 = rp0 + 32 * 256;
        #pragma unroll
        for (int kc = 0; kc < 8; kc++) {
            Rh0[kc] = *(const f16x8*)(rp0 + kc * 16);
            Rl0[kc] = *(const f16x8*)(rp0 + 128 + kc * 16);
            Rh1[kc] = *(const f16x8*)(rp1 + kc * 16);
            Rl1[kc] = *(const f16x8*)(rp1 + 128 + kc * 16);
        }
    }

    float best0 = 3.402823466e+38f, best1 = 3.402823466e+38f;
    int bidx0 = 0, bidx1 = 0;

    auto STAGE = [&](int gch, int b) {
        const _Float16* gp = Esp + (size_t)gch * 16384;
        #pragma unroll
        for (int p = 0; p < 8; p++) {
            int f = tid + 256 * p;
            __builtin_amdgcn_global_load_lds(
                (const __attribute__((address_space(1))) void*)(gp + (size_t)f * 8),
                (__attribute__((address_space(3))) void*)(&Es[b][(size_t)f * 8]),
                16, 0, 0);
        }
    };

    STAGE(ch0, 0);
    for (int ch = 0; ch < 16; ch++) {
        const int buf = ch & 1;
        const int c0c = cbase + ch * 64;
        // cbn for both 32-code subtiles, loaded BEFORE the barrier
        float cnv0[16], cnv1[16];
        #pragma unroll
        for (int q = 0; q < 4; q++) {
            float4 v0 = *(const float4*)(cbnS + c0c + q * 8 + 4 * g);
            float4 v1 = *(const float4*)(cbnS + c0c + 32 + q * 8 + 4 * g);
            cnv0[q * 4 + 0] = v0.x; cnv0[q * 4 + 1] = v0.y;
            cnv0[q * 4 + 2] = v0.z; cnv0[q * 4 + 3] = v0.w;
            cnv1[q * 4 + 0] = v1.x; cnv1[q * 4 + 1] = v1.y;
            cnv1[q * 4 + 2] = v1.z; cnv1[q * 4 + 3] = v1.w;
        }
        __syncthreads();                      // stage(ch) landed; buf readable
        if (ch < 15) STAGE(ch0 + ch + 1, buf ^ 1);
        #pragma unroll
        for (int st = 0; st < 2; st++) {
            const int cloc = st * 32 + cl31;
            const float* cnv = st ? cnv1 : cnv0;
            f32x16 c00, c01, c10, c11;
            #pragma unroll
            for (int m = 0; m < 16; m++) { c00[m] = 0.f; c01[m] = 0.f; c10[m] = 0.f; c11[m] = 0.f; }
            __builtin_amdgcn_s_setprio(1);
            #pragma unroll
            for (int kc = 0; kc < 8; kc++) {
                int sh = kc * 2 + g;
                f16x8 eh = *(const f16x8*)&Es[buf][sh * 512 + cloc * 8];
                f16x8 el = *(const f16x8*)&Es[buf][(16 + sh) * 512 + cloc * 8];
                c00 = __builtin_amdgcn_mfma_f32_32x32x16_f16(eh, Rh0[kc], c00, 0, 0, 0);
                c01 = __builtin_amdgcn_mfma_f32_32x32x16_f16(eh, Rh1[kc], c01, 0, 0, 0);
                c10 = __builtin_amdgcn_mfma_f32_32x32x16_f16(eh, Rl0[kc], c10, 0, 0, 0);
                c00 = __builtin_amdgcn_mfma_f32_32x32x16_f16(el, Rh0[kc], c00, 0, 0, 0);
                c01 = __builtin_amdgcn_mfma_f32_32x32x16_f16(el, Rh1[kc], c01, 0, 0, 0);
                c11 = __builtin_amdgcn_mfma_f32_32x32x16_f16(eh, Rl1[kc], c11, 0, 0, 0);
            }
            __builtin_amdgcn_s_setprio(0);
            // running argmin (D-row m -> code c0c + st*32 + 4g + (m&3)+8*(m>>2))
            const int c0g = c0c + st * 32 + 4 * g;
            #pragma unroll
            for (int m = 0; m < 16; m++) {
                int c = c0g + ((m & 3) + 8 * (m >> 2));
                float s0 = (c00[m] + c10[m]) + cnv[m];
                float s1 = (c01[m] + c11[m]) + cnv[m];
                if (s0 < best0) { best0 = s0; bidx0 = c; }
                if (s1 < best1) { best1 = s1; bidx1 = c; }
            }
        }
    }

    // merge lane-halves (same row, complementary code sets); tie -> smaller idx
    {
        float ob = __shfl_xor(best0, 32, 64);
        int oi = __shfl_xor(bidx0, 32, 64);
        if (ob < best0 || (ob == best0 && oi < bidx0)) { best0 = ob; bidx0 = oi; }
        ob = __shfl_xor(best1, 32, 64);
        oi = __shfl_xor(bidx1, 32, 64);
        if (ob < best1 || (ob == best1 && oi < bidx1)) { best1 = ob; bidx1 = oi; }
    }
    if (lane < 32) {
        const int part = blockIdx.y;
        pbest[(size_t)part * NB + rt0 + cl31] = best0;
        pidx [(size_t)part * NB + rt0 + cl31] = bidx0;
        pbest[(size_t)part * NB + rt0 + 32 + cl31] = best1;
        pidx [(size_t)part * NB + rt0 + 32 + cl31] = bidx1;
    }
}

// fused strip-merge + gather + residual update + qsum + vq_loss partial (v5):
// 8-strip merge via 3-step shfl_xor (strip = lane&7; each octet holds all 8
// strips; exact associative tie-break). lastq skips dead Rout/Rsp writes.
__global__ void k_vq_update(const float* __restrict__ Rin,
                            const float* __restrict__ pbest, const int* __restrict__ pidx,
                            const float* __restrict__ E, float* __restrict__ Rout,
                            float* __restrict__ qsum, float* __restrict__ part,
                            int firstq, int lastq, _Float16* __restrict__ Rsp,
                            float* __restrict__ ids_f) {
    __shared__ float ps[4];
    int t = blockIdx.x * 256 + threadIdx.x;   // NB*128/8 threads
    int i0 = t * 8;
    int row = i0 >> 7, d0 = i0 & 127;
    int lane = threadIdx.x & 63;
    // strip-merge: this thread owns strip s = lane&7 of its row
    float b = pbest[(size_t)(lane & 7) * NB + row];
    int bi = pidx[(size_t)(lane & 7) * NB + row];
    #pragma unroll
    for (int m = 1; m < 8; m <<= 1) {
        float ob = __shfl_xor(b, m, 64);
        int oi = __shfl_xor(bi, m, 64);
        if (ob < b || (ob == b && oi < bi)) { b = ob; bi = oi; }
    }
    if (d0 == 0) ids_f[(size_t)row * 4] = (float)bi;
    const float* ep = E + (size_t)bi * 128 + d0;
    float4 e0 = *(const float4*)ep, e1 = *(const float4*)(ep + 4);
    float4 r0 = *(const float4*)&Rin[i0], r1 = *(const float4*)&Rin[i0 + 4];
    float rv[8] = {r0.x - e0.x, r0.y - e0.y, r0.z - e0.z, r0.w - e0.w,
                   r1.x - e1.x, r1.y - e1.y, r1.z - e1.z, r1.w - e1.w};
    if (!lastq) {
        *(float4*)&Rout[i0]     = make_float4(rv[0], rv[1], rv[2], rv[3]);
        *(float4*)&Rout[i0 + 4] = make_float4(rv[4], rv[5], rv[6], rv[7]);
    }
    if (firstq) {
        *(float4*)&qsum[i0] = e0;
        *(float4*)&qsum[i0 + 4] = e1;
    } else {
        float4 q0 = *(const float4*)&qsum[i0], q1 = *(const float4*)&qsum[i0 + 4];
        *(float4*)&qsum[i0]     = make_float4(q0.x + e0.x, q0.y + e0.y, q0.z + e0.z, q0.w + e0.w);
        *(float4*)&qsum[i0 + 4] = make_float4(q1.x + e1.x, q1.y + e1.y, q1.z + e1.z, q1.w + e1.w);
    }
    float p = 0.f;
    if (!lastq) {
        f16x8 hi, lo;
        #pragma unroll
        for (int j = 0; j < 8; j++) {
            float rs = rv[j] * -32.f;
            _Float16 h = (_Float16)rs;
            hi[j] = h;
            lo[j] = (_Float16)(rs - (float)h);
            p = fmaf(rv[j], rv[j], p);
        }
        *(f16x8*)&Rsp[(size_t)row * 256 + d0] = hi;
        *(f16x8*)&Rsp[(size_t)row * 256 + 128 + d0] = lo;
    } else {
        #pragma unroll
        for (int j = 0; j < 8; j++) p = fmaf(rv[j], rv[j], p);
    }
    #pragma unroll
    for (int m = 1; m < 64; m <<= 1) p += __shfl_xor(p, m, 64);
    int wv = threadIdx.x >> 6;
    if (lane == 0) ps[wv] = p;
    __syncthreads();
    if (threadIdx.x == 0)
        part[blockIdx.x] = (ps[0] + ps[1]) + (ps[2] + ps[3]);
}

// ---------------- launch ----------------

extern "C" void kernel_launch(void* const* d_in, const int* in_sizes, int n_in,
                              void* d_out, int out_size, void* d_ws, size_t ws_size,
                              hipStream_t stream) {
    (void)in_sizes; (void)n_in; (void)out_size; (void)ws_size;
    const float* x        = (const float*)d_in[0];
    const float* emb_mean = (const float*)d_in[1];
    const float* emb_std  = (const float*)d_in[2];
    const float* enc_w0 = (const float*)d_in[3];
    const float* enc_b0 = (const float*)d_in[4];
    const float* enc_g0 = (const float*)d_in[5];
    const float* enc_w1 = (const float*)d_in[6];
    const float* enc_b1 = (const float*)d_in[7];
    const float* enc_g1 = (const float*)d_in[8];
    const float* enc_w2 = (const float*)d_in[9];
    const float* enc_b2 = (const float*)d_in[10];
    const float* enc_g2 = (const float*)d_in[11];
    const float* cb     = (const float*)d_in[12];
    const float* dec_w0 = (const float*)d_in[13];
    const float* dec_b0 = (const float*)d_in[14];
    const float* dec_g0 = (const float*)d_in[15];
    const float* dec_w1 = (const float*)d_in[16];
    const float* dec_b1 = (const float*)d_in[17];
    const float* dec_g1 = (const float*)d_in[18];
    const float* dec_w2 = (const float*)d_in[19];
    const float* dec_b2 = (const float*)d_in[20];

    float* out   = (float*)d_out;
    float* xn    = out;                        // recon region doubles as xn scratch
    float* ids_f = out + (size_t)NB * DIN;
    float* rl    = out + (size_t)NB * DIN + (size_t)NB * 4;
    float* vl    = rl + 1;

    float* ws   = (float*)d_ws;
    float* h0   = ws;                           // 16384*512
    float* h1   = h0 + (size_t)NB * 512;        // 16384*256
    float* h2   = h1 + (size_t)NB * 256;        // 16384*128
    float* rbuf = h2 + (size_t)NB * 128;        // 16384*128
    float* qsum = rbuf + (size_t)NB * 128;      // 16384*128
    float* cbn  = qsum + (size_t)NB * 128;      // 4*8192
    int*   idxb = (int*)(cbn + 4 * 8192);       // 16384 (unused, layout keep)
    float* vqp  = (float*)(idxb + NB);          // 4*1024 loss partials

    // VQ scratch in h0 (free between enc1-read and dec1-write):
    float*    pbest = h0;                                   // 8*16384
    int*      pidx  = (int*)(h0 + 16 * (size_t)NB);         // 8*16384
    _Float16* Rsp   = (_Float16*)(h0 + 32 * (size_t)NB);
    _Float16* Esp   = (_Float16*)(h0 + 32 * (size_t)NB + (size_t)NB * 128);

    // weight splits live in rbuf: enc set dead before VQ writes rbuf (q=0
    // update); dec set written after the last vq_update reads rbuf.
    _Float16* WtE0 = (_Float16*)rbuf;           // 768*512*2 = 786432 halfs
    _Float16* WtE1 = WtE0 + 786432;             // 512*256*2 = 262144
    _Float16* WtE2 = WtE0 + 1048576;            // 256*128*2 =  65536
    _Float16* WtD0 = (_Float16*)rbuf;           // 128*256*2 =  65536
    _Float16* WtD1 = WtD0 + 65536;              // 256*512*2 = 262144
    _Float16* WtD2 = WtD0 + 327680;             // 512*768*2 = 786432

    // merged input-norm (+rl zero) + enc weight splits: 49152 + 2176 blocks
    k_norm_wsplit<<<51328, 256, 0, stream>>>(x, emb_mean, emb_std, xn, rl,
                                             enc_w0, WtE0, enc_w1, WtE1, enc_w2, WtE2);

    k_mfma_rms<512><<<NB / 64, 512, 0, stream>>>(xn, WtE0, enc_b0, enc_g0, h0, 768, nullptr);
    k_mfma_rms<256><<<NB / 64, 512, 0, stream>>>(h0, WtE1, enc_b1, enc_g1, h1, 512, nullptr);
    // enc2 also emits the fp16 hi/lo split (scale -32)
    k_mfma_rms<128><<<NB / 64, 512, 0, stream>>>(h1, WtE2, enc_b2, enc_g2, h2, 256, Rsp);

    // fused cbnorm + esplit (into h0 region, after enc1 consumed h0)
    k_cbesplit<<<(4 * 8192) / 4, 256, 0, stream>>>(cb, cbn, Esp);

    for (int q = 0; q < 4; q++) {
        const float* R = (q == 0) ? h2 : rbuf;
        const float* Eq = cb + (size_t)q * 8192 * 128;
        const _Float16* EspQ = Esp + (size_t)q * 2097152;
        dim3 gq(NB / 256, 8);
        k_vq_argmin_mfma<<<gq, 256, 0, stream>>>(Rsp, EspQ, cbn + q * 8192, pbest, pidx);
        k_vq_update<<<(NB * 128) / 2048, 256, 0, stream>>>(R, pbest, pidx, Eq, rbuf, qsum,
                                                           vqp + q * 1024, q == 0 ? 1 : 0,
                                                           q == 3 ? 1 : 0, Rsp, ids_f + q);
    }

    // merged dec weight splits + vq_loss accumulation (block 2176 = acc)
    k_wsplit_acc<<<2177, 256, 0, stream>>>(dec_w0, WtD0, dec_w1, WtD1, dec_w2, WtD2,
                                           vqp, vl);

    k_mfma_rms<256><<<NB / 64, 512, 0, stream>>>(qsum, WtD0, dec_b0, dec_g0, h1, 128, nullptr);
    k_mfma_rms<512><<<NB / 64, 512, 0, stream>>>(h1, WtD1, dec_b1, dec_g1, h0, 256, nullptr);

    dim3 g2(NB / 64, 3);
    k_mfma_dec2<<<g2, 512, 0, stream>>>(h0, WtD2, dec_b2, xn, rl, 512);
}